// Round 1
// baseline (3073.036 us; speedup 1.0000x reference)
//
#include <hip/hip_runtime.h>
#include <math.h>

#define L_TOK 5440
#define NTOK  10880   // B * L
#define D     256

// ---------------- flatten: src/pos (B,d,H,W) -> (B,L,d), pos += level_embed ----------------
__global__ __launch_bounds__(256) void flatten_kernel(
    const float* __restrict__ s0, const float* __restrict__ p0,
    const float* __restrict__ s1, const float* __restrict__ p1,
    const float* __restrict__ s2, const float* __restrict__ p2,
    const float* __restrict__ s3, const float* __restrict__ p3,
    const float* __restrict__ lvl_emb,
    float* __restrict__ x, float* __restrict__ pos)
{
    int bl = blockIdx.x;
    int b = bl / L_TOK, l = bl - b * L_TOK;
    int c = threadIdx.x;
    int lv, r, S;
    const float *sp, *pp;
    if (l < 4096)      { lv = 0; r = l;        S = 64; sp = s0; pp = p0; }
    else if (l < 5120) { lv = 1; r = l - 4096; S = 32; sp = s1; pp = p1; }
    else if (l < 5376) { lv = 2; r = l - 5120; S = 16; sp = s2; pp = p2; }
    else               { lv = 3; r = l - 5376; S = 8;  sp = s3; pp = p3; }
    int HW = S * S;
    size_t si = ((size_t)b * D + c) * HW + r;
    x[(size_t)bl * D + c]   = sp[si];
    pos[(size_t)bl * D + c] = pp[si] + lvl_emb[lv * D + c];
}

// ---------------- LayerNorm (one wave per token, d=256 -> 4 elems/lane) ----------------
__global__ __launch_bounds__(256) void ln_kernel(
    const float* __restrict__ x, const float* __restrict__ g, const float* __restrict__ bta,
    const float* __restrict__ pos, float* __restrict__ out)
{
    int wid = threadIdx.x >> 6, lane = threadIdx.x & 63;
    int m = blockIdx.x * 4 + wid;
    const float* xr = x + (size_t)m * D;
    float v[4];
#pragma unroll
    for (int i = 0; i < 4; ++i) v[i] = xr[lane + i * 64];
    float s = v[0] + v[1] + v[2] + v[3];
#pragma unroll
    for (int o = 32; o; o >>= 1) s += __shfl_xor(s, o);
    float mean = s * (1.0f / D);
    float sq = 0.0f;
#pragma unroll
    for (int i = 0; i < 4; ++i) { float d = v[i] - mean; sq += d * d; }
#pragma unroll
    for (int o = 32; o; o >>= 1) sq += __shfl_xor(sq, o);
    float rstd = rsqrtf(sq * (1.0f / D) + 1e-5f);
    float* orow = out + (size_t)m * D;
#pragma unroll
    for (int i = 0; i < 4; ++i) {
        int c = lane + i * 64;
        float o = (v[i] - mean) * rstd * g[c] + bta[c];
        if (pos) o += pos[(size_t)m * D + c];
        orow[c] = o;
    }
}

// ---------------- generic fp32 GEMM: C = act(A[M,K] @ W[K,N] + bias) (+resid) ----------------
// BM=BN=64, BK=32, 256 threads, 4x4 per thread. M,N,K multiples of 64/32.
__global__ __launch_bounds__(256) void gemm_kernel(
    const float* __restrict__ A, const float* __restrict__ W,
    const float* __restrict__ bias, const float* __restrict__ resid,
    float* __restrict__ C, int N, int K, int ldc, int act)
{
    __shared__ float As[64][33];
    __shared__ float Bs[32][64];
    int row0 = blockIdx.y * 64, col0 = blockIdx.x * 64;
    int tid = threadIdx.x, tx = tid & 15, ty = tid >> 4;
    float acc[4][4] = {};

    for (int k0 = 0; k0 < K; k0 += 32) {
        for (int f = tid; f < 512; f += 256) {
            int r = f >> 3, c4 = (f & 7) * 4;
            const float4 va = *reinterpret_cast<const float4*>(&A[(size_t)(row0 + r) * K + k0 + c4]);
            As[r][c4] = va.x; As[r][c4 + 1] = va.y; As[r][c4 + 2] = va.z; As[r][c4 + 3] = va.w;
        }
        for (int f = tid; f < 512; f += 256) {
            int r = f >> 4, c4 = (f & 15) * 4;
            *reinterpret_cast<float4*>(&Bs[r][c4]) =
                *reinterpret_cast<const float4*>(&W[(size_t)(k0 + r) * N + col0 + c4]);
        }
        __syncthreads();
#pragma unroll
        for (int kk = 0; kk < 32; ++kk) {
            float a0 = As[ty * 4 + 0][kk];
            float a1 = As[ty * 4 + 1][kk];
            float a2 = As[ty * 4 + 2][kk];
            float a3 = As[ty * 4 + 3][kk];
            float4 bv = *reinterpret_cast<const float4*>(&Bs[kk][tx * 4]);
            acc[0][0] += a0 * bv.x; acc[0][1] += a0 * bv.y; acc[0][2] += a0 * bv.z; acc[0][3] += a0 * bv.w;
            acc[1][0] += a1 * bv.x; acc[1][1] += a1 * bv.y; acc[1][2] += a1 * bv.z; acc[1][3] += a1 * bv.w;
            acc[2][0] += a2 * bv.x; acc[2][1] += a2 * bv.y; acc[2][2] += a2 * bv.z; acc[2][3] += a2 * bv.w;
            acc[3][0] += a3 * bv.x; acc[3][1] += a3 * bv.y; acc[3][2] += a3 * bv.z; acc[3][3] += a3 * bv.w;
        }
        __syncthreads();
    }

#pragma unroll
    for (int i = 0; i < 4; ++i) {
        int r = row0 + ty * 4 + i;
#pragma unroll
        for (int j = 0; j < 4; ++j) {
            int c = col0 + tx * 4 + j;
            float v = acc[i][j] + bias[c];
            if (act) v = 0.5f * v * (1.0f + erff(v * 0.70710678118654752f));
            if (resid) v += resid[(size_t)r * ldc + c];
            C[(size_t)r * ldc + c] = v;
        }
    }
}

// ---------------- softmax over 32 logits per (token, head), in-place in big[:,512:768] ----------------
__global__ __launch_bounds__(256) void softmax_kernel(float* __restrict__ big)
{
    int rid = blockIdx.x * 256 + threadIdx.x;   // < NTOK*8
    int m = rid >> 3, h = rid & 7;
    float* row = big + (size_t)m * 768 + 512 + h * 32;
    float v[32];
    float mx = -1e30f;
#pragma unroll
    for (int i = 0; i < 32; ++i) { v[i] = row[i]; mx = fmaxf(mx, v[i]); }
    float s = 0.0f;
#pragma unroll
    for (int i = 0; i < 32; ++i) { v[i] = __expf(v[i] - mx); s += v[i]; }
    float inv = 1.0f / s;
#pragma unroll
    for (int i = 0; i < 32; ++i) row[i] = v[i] * inv;
}

// ---------------- deformable sampling ----------------
// big row: [0:512) = off (h,lv,p,2), [512:768) = attn (h, lv*8+p) post-softmax
// val: (B, L, 256) with channel = head*32+e ; out: (B,L,256)
__global__ __launch_bounds__(256) void sample_kernel(
    const float* __restrict__ big, const float* __restrict__ val, float* __restrict__ out)
{
    __shared__ float sw[256 * 4];
    __shared__ int   si[256 * 4];
    int bl = blockIdx.x;
    int b = bl / L_TOK, l = bl - b * L_TOK;
    const float* row = big + (size_t)bl * 768;
    int t = threadIdx.x;
    {
        int head = t >> 5, lvp = t & 31, lv = lvp >> 3, p = lvp & 7;
        int r, Sq;
        if (l < 4096)      { r = l;        Sq = 64; }
        else if (l < 5120) { r = l - 4096; Sq = 32; }
        else if (l < 5376) { r = l - 5120; Sq = 16; }
        else               { r = l - 5376; Sq = 8;  }
        float refx = ((r % Sq) + 0.5f) / (float)Sq;
        float refy = ((r / Sq) + 0.5f) / (float)Sq;
        int S = 64 >> lv;
        int start = (lv == 0) ? 0 : (lv == 1) ? 4096 : (lv == 2) ? 5120 : 5376;
        float Sf = (float)S;
        float a  = row[512 + head * 32 + lvp];
        float ox = row[head * 64 + lv * 16 + p * 2 + 0];
        float oy = row[head * 64 + lv * 16 + p * 2 + 1];
        float X = (refx + ox / Sf) * Sf - 0.5f;
        float Y = (refy + oy / Sf) * Sf - 0.5f;
        float x0 = floorf(X), y0 = floorf(Y);
        float fx = X - x0, fy = Y - y0;
        int xi0 = (int)x0, yi0 = (int)y0;
#pragma unroll
        for (int tap = 0; tap < 4; ++tap) {
            int dx = tap & 1, dy = tap >> 1;
            int xi = xi0 + dx, yi = yi0 + dy;
            float w = (dx ? fx : 1.0f - fx) * (dy ? fy : 1.0f - fy);
            bool valid = (xi >= 0) && (xi < S) && (yi >= 0) && (yi < S);
            int xc = xi < 0 ? 0 : (xi > S - 1 ? S - 1 : xi);
            int yc = yi < 0 ? 0 : (yi > S - 1 ? S - 1 : yi);
            sw[t * 4 + tap] = valid ? w * a : 0.0f;
            si[t * 4 + tap] = start + yc * S + xc;
        }
    }
    __syncthreads();
    int head = t >> 5, e = t & 31;
    const float* vb = val + (size_t)b * L_TOK * D + head * 32 + e;
    float acc = 0.0f;
    int base = head * 32 * 4;
    for (int s = 0; s < 32; ++s) {
#pragma unroll
        for (int tap = 0; tap < 4; ++tap) {
            float w   = sw[base + s * 4 + tap];
            int   idx = si[base + s * 4 + tap];
            acc += w * vb[(size_t)idx * D];
        }
    }
    out[(size_t)bl * D + t] = acc;
}

// ---------------- orchestration ----------------
extern "C" void kernel_launch(void* const* d_in, const int* in_sizes, int n_in,
                              void* d_out, int out_size, void* d_ws, size_t ws_size,
                              hipStream_t stream)
{
    // setup_inputs() dict order: src0,pos0,src1,pos1,src2,pos2,src3,pos3, level_embed,
    // W_off,b_off,W_attn,b_attn,W_val,b_val,W_out,b_out, ln1_g,ln1_b, W1,b1,W2,b2, ln2_g,ln2_b
    const float* s0    = (const float*)d_in[0];
    const float* p0    = (const float*)d_in[1];
    const float* s1    = (const float*)d_in[2];
    const float* p1    = (const float*)d_in[3];
    const float* s2    = (const float*)d_in[4];
    const float* p2    = (const float*)d_in[5];
    const float* s3    = (const float*)d_in[6];
    const float* p3    = (const float*)d_in[7];
    const float* lvl   = (const float*)d_in[8];
    const float* W_off = (const float*)d_in[9];
    const float* b_off = (const float*)d_in[10];
    const float* W_att = (const float*)d_in[11];
    const float* b_att = (const float*)d_in[12];
    const float* W_val = (const float*)d_in[13];
    const float* b_val = (const float*)d_in[14];
    const float* W_out = (const float*)d_in[15];
    const float* b_out = (const float*)d_in[16];
    const float* ln1g  = (const float*)d_in[17];
    const float* ln1b  = (const float*)d_in[18];
    const float* W1    = (const float*)d_in[19];
    const float* b1    = (const float*)d_in[20];
    const float* W2    = (const float*)d_in[21];
    const float* b2    = (const float*)d_in[22];
    const float* ln2g  = (const float*)d_in[23];
    const float* ln2b  = (const float*)d_in[24];

    const size_t S1 = (size_t)NTOK * D;   // floats per (B,L,256) buffer
    float* xbuf = (float*)d_ws;           // persistent x
    float* pos  = xbuf + S1;              // persistent pos_flat
    float* q    = pos + S1;               // q / x2 (reused)
    float* val  = q + S1;                 // value projection
    float* samp = val + S1;               // sampling output
    float* big  = samp + S1;              // 4*S1: off+attn (ld 768) then ffn hidden (ld 1024)

    flatten_kernel<<<NTOK, 256, 0, stream>>>(s0, p0, s1, p1, s2, p2, s3, p3, lvl, xbuf, pos);

    for (int i = 0; i < 6; ++i) {
        // q = LN1(x) + pos
        ln_kernel<<<NTOK / 4, 256, 0, stream>>>(xbuf, ln1g + i * 256, ln1b + i * 256, pos, q);
        // off = q @ W_off + b_off   -> big[:, 0:512)
        gemm_kernel<<<dim3(8, NTOK / 64), 256, 0, stream>>>(
            q, W_off + (size_t)i * 256 * 512, b_off + (size_t)i * 512, nullptr, big, 512, 256, 768, 0);
        // attn logits = q @ W_attn + b_attn -> big[:, 512:768)
        gemm_kernel<<<dim3(4, NTOK / 64), 256, 0, stream>>>(
            q, W_att + (size_t)i * 256 * 256, b_att + (size_t)i * 256, nullptr, big + 512, 256, 256, 768, 0);
        // val = x @ W_val + b_val
        gemm_kernel<<<dim3(4, NTOK / 64), 256, 0, stream>>>(
            xbuf, W_val + (size_t)i * 256 * 256, b_val + (size_t)i * 256, nullptr, val, 256, 256, 256, 0);
        // softmax on attn section
        softmax_kernel<<<NTOK * 8 / 256, 256, 0, stream>>>(big);
        // deformable sampling
        sample_kernel<<<NTOK, 256, 0, stream>>>(big, val, samp);
        // x = x + samp @ W_out + b_out
        gemm_kernel<<<dim3(4, NTOK / 64), 256, 0, stream>>>(
            samp, W_out + (size_t)i * 256 * 256, b_out + (size_t)i * 256, xbuf, xbuf, 256, 256, 256, 0);
        // x2 = LN2(x)  (reuse q)
        ln_kernel<<<NTOK / 4, 256, 0, stream>>>(xbuf, ln2g + i * 256, ln2b + i * 256, nullptr, q);
        // h = gelu(x2 @ W1 + b1)
        gemm_kernel<<<dim3(16, NTOK / 64), 256, 0, stream>>>(
            q, W1 + (size_t)i * 256 * 1024, b1 + (size_t)i * 1024, nullptr, big, 1024, 256, 1024, 1);
        // x = x + h @ W2 + b2   (last layer writes straight to d_out)
        float* outp = (i == 5) ? (float*)d_out : xbuf;
        gemm_kernel<<<dim3(4, NTOK / 64), 256, 0, stream>>>(
            big, W2 + (size_t)i * 1024 * 256, b2 + (size_t)i * 256, xbuf, outp, 256, 1024, 256, 0);
    }
}

// Round 3
// 1256.335 us; speedup vs baseline: 2.4460x; 2.4460x over previous
//
#include <hip/hip_runtime.h>
#include <hip/hip_bf16.h>
#include <math.h>

#define L_TOK 5440
#define NTOK  10880   // B * L
#define D     256

typedef __attribute__((ext_vector_type(8))) short short8;
typedef __attribute__((ext_vector_type(4))) float f32x4;

__device__ __forceinline__ short f2bf(float f) {
    __hip_bfloat16 h = __float2bfloat16(f);
    return __builtin_bit_cast(short, h);
}

// ---------------- flatten via LDS transpose: src/pos (B,d,H,W) -> (B,L,d), pos += level_embed ----
__global__ __launch_bounds__(256) void flat_kernel(
    const float* __restrict__ s, const float* __restrict__ p, const float* __restrict__ le,
    float* __restrict__ x, float* __restrict__ pos, int HW, int start, int lv)
{
    __shared__ float ts[32][33], tp[32][33];
    int b = blockIdx.z, c0 = blockIdx.y * 32, pix0 = blockIdx.x * 32;
    int tx = threadIdx.x & 31, ty = threadIdx.x >> 5;
#pragma unroll
    for (int i = 0; i < 4; ++i) {
        int c = c0 + ty + i * 8;
        size_t gi = ((size_t)b * D + c) * HW + pix0 + tx;
        ts[ty + i * 8][tx] = s[gi];
        tp[ty + i * 8][tx] = p[gi];
    }
    __syncthreads();
#pragma unroll
    for (int i = 0; i < 4; ++i) {
        int pix = pix0 + ty + i * 8;
        size_t bl = (size_t)b * L_TOK + start + pix;
        int c = c0 + tx;
        x[bl * D + c]   = ts[tx][ty + i * 8];
        pos[bl * D + c] = tp[tx][ty + i * 8] + le[lv * D + c];
    }
}

// ---------------- weight convert+transpose: W (depth,K,N) f32 -> Wt (depth,N,K) bf16 ----------
__global__ __launch_bounds__(256) void wconv_kernel(
    const float* __restrict__ W, short* __restrict__ Wt, int K, int N)
{
    __shared__ float tile[32][33];
    int d = blockIdx.z;
    int n0 = blockIdx.x * 32, k0 = blockIdx.y * 32;
    const float* Wd = W + (size_t)d * K * N;
    short* Wtd = Wt + (size_t)d * K * N;
    int tx = threadIdx.x & 31, ty = threadIdx.x >> 5;
#pragma unroll
    for (int i = 0; i < 4; ++i)
        tile[ty + i * 8][tx] = Wd[(size_t)(k0 + ty + i * 8) * N + n0 + tx];
    __syncthreads();
#pragma unroll
    for (int i = 0; i < 4; ++i)
        Wtd[(size_t)(n0 + ty + i * 8) * K + k0 + tx] = f2bf(tile[tx][ty + i * 8]);
}

// ---------------- LayerNorm (one wave per token, d=256 -> 4 elems/lane) ----------------
__global__ __launch_bounds__(256) void ln_kernel(
    const float* __restrict__ x, const float* __restrict__ g, const float* __restrict__ bta,
    const float* __restrict__ pos, float* __restrict__ out)
{
    int wid = threadIdx.x >> 6, lane = threadIdx.x & 63;
    int m = blockIdx.x * 4 + wid;
    const float* xr = x + (size_t)m * D;
    float v[4];
#pragma unroll
    for (int i = 0; i < 4; ++i) v[i] = xr[lane + i * 64];
    float s = v[0] + v[1] + v[2] + v[3];
#pragma unroll
    for (int o = 32; o; o >>= 1) s += __shfl_xor(s, o);
    float mean = s * (1.0f / D);
    float sq = 0.0f;
#pragma unroll
    for (int i = 0; i < 4; ++i) { float d = v[i] - mean; sq += d * d; }
#pragma unroll
    for (int o = 32; o; o >>= 1) sq += __shfl_xor(sq, o);
    float rstd = rsqrtf(sq * (1.0f / D) + 1e-5f);
    float* orow = out + (size_t)m * D;
#pragma unroll
    for (int i = 0; i < 4; ++i) {
        int c = lane + i * 64;
        float o = (v[i] - mean) * rstd * g[c] + bta[c];
        if (pos) o += pos[(size_t)m * D + c];
        orow[c] = o;
    }
}

// ---------------- bf16 MFMA GEMM: C = act(A[M,K]f32 @ Wt[N,K]bf16^T + bias) (+resid) ----------
// 128x128 tile, BK=32, 256 threads = 4 waves (2x2), each wave 64x64 via 4x4 mfma_16x16x32.
// LDS tiles [128][32] bf16. Row = 64 bytes; XOR swizzle byte ^= (((row>>1)&3)<<4):
// bijective within the row (2-bit XOR on the four 16B slots), and a wave's fragment read
// (16 consecutive rows, one 16B slot) collides only rows r/r+8 -> 2-way = free (m136).
__global__ __launch_bounds__(256) void mm_kernel(
    const float* __restrict__ A, const short* __restrict__ Wt,
    const float* __restrict__ bias, const float* __restrict__ resid,
    float* __restrict__ C, int N, int K, int ldc, int act)
{
    __shared__ short As[128 * 32];
    __shared__ short Bs[128 * 32];
    int row0 = blockIdx.y * 128, col0 = blockIdx.x * 128;
    int tid = threadIdx.x;
    int lane = tid & 63, w = tid >> 6;
    int wr = w >> 1, wc = w & 1;
    int l15 = lane & 15, l16 = lane >> 4;

    // per-lane LDS fragment offsets (short units), constant across k-loop
    int a_off[4], b_off[4];
#pragma unroll
    for (int m = 0; m < 4; ++m) {
        int ra = wr * 64 + m * 16 + l15;
        a_off[m] = ra * 32 + ((((l16 * 16)) ^ (((ra >> 1) & 3) << 4)) >> 1);
        int rb = wc * 64 + m * 16 + l15;
        b_off[m] = rb * 32 + ((((l16 * 16)) ^ (((rb >> 1) & 3) << 4)) >> 1);
    }
    int sr = tid >> 2, skb = (tid & 3) * 8;   // staging: row, k-element base (8 elems/thread)

    f32x4 acc[4][4];
#pragma unroll
    for (int m = 0; m < 4; ++m)
#pragma unroll
        for (int n = 0; n < 4; ++n) acc[m][n] = (f32x4){0.f, 0.f, 0.f, 0.f};

    for (int k0 = 0; k0 < K; k0 += 32) {
#pragma unroll
        for (int it = 0; it < 2; ++it) {
            int r = sr + it * 64;
            int soff = r * 32 + ((((skb * 2)) ^ (((r >> 1) & 3) << 4)) >> 1);
            const float* ap = &A[(size_t)(row0 + r) * K + k0 + skb];
            float4 v0 = *(const float4*)ap;
            float4 v1 = *(const float4*)(ap + 4);
            short8 sv;
            sv[0] = f2bf(v0.x); sv[1] = f2bf(v0.y); sv[2] = f2bf(v0.z); sv[3] = f2bf(v0.w);
            sv[4] = f2bf(v1.x); sv[5] = f2bf(v1.y); sv[6] = f2bf(v1.z); sv[7] = f2bf(v1.w);
            *(short8*)&As[soff] = sv;
            *(short8*)&Bs[soff] = *(const short8*)&Wt[(size_t)(col0 + r) * K + k0 + skb];
        }
        __syncthreads();
        short8 af[4], bfr[4];
#pragma unroll
        for (int m = 0; m < 4; ++m) af[m] = *(short8*)&As[a_off[m]];
#pragma unroll
        for (int n = 0; n < 4; ++n) bfr[n] = *(short8*)&Bs[b_off[n]];
#pragma unroll
        for (int m = 0; m < 4; ++m)
#pragma unroll
            for (int n = 0; n < 4; ++n)
                acc[m][n] = __builtin_amdgcn_mfma_f32_16x16x32_bf16(af[m], bfr[n], acc[m][n], 0, 0, 0);
        __syncthreads();
    }

#pragma unroll
    for (int m = 0; m < 4; ++m) {
#pragma unroll
        for (int j = 0; j < 4; ++j) {
            int row = row0 + wr * 64 + m * 16 + l16 * 4 + j;
#pragma unroll
            for (int n = 0; n < 4; ++n) {
                int col = col0 + wc * 64 + n * 16 + l15;
                float v = acc[m][n][j] + bias[col];
                if (act) v = 0.5f * v * (1.0f + erff(v * 0.70710678118654752f));
                if (resid) v += resid[(size_t)row * ldc + col];
                C[(size_t)row * ldc + col] = v;
            }
        }
    }
}

// ---------------- deformable sampling (softmax fused, float4 gathers) ----------------
// big row: [0:512) = off (h,lv,p,2), [512:768) = attn logits (h, lv*8+p)
// phase1: t = h*32+lvp computes softmax weight * bilinear taps -> LDS
// phase2: t = h*32 + qt*8 + cg : float4 over channels cg*4, 8 samples each, shfl-reduce over qt
__global__ __launch_bounds__(256) void sample_kernel(
    const float* __restrict__ big, const float* __restrict__ val, float* __restrict__ out)
{
    __shared__ float sw[256 * 4];
    __shared__ int   si[256 * 4];
    int bl = blockIdx.x;
    int b = bl / L_TOK, l = bl - b * L_TOK;
    const float* row = big + (size_t)bl * 768;
    int t = threadIdx.x;
    {
        int head = t >> 5, lvp = t & 31, lv = lvp >> 3, p = lvp & 7;
        int lq, r;
        if (l < 4096)      { lq = 0; r = l;        }
        else if (l < 5120) { lq = 1; r = l - 4096; }
        else if (l < 5376) { lq = 2; r = l - 5120; }
        else               { lq = 3; r = l - 5376; }
        int sh = 6 - lq;
        float invSq = 1.0f / (float)(1 << sh);
        float refx = ((r & ((1 << sh) - 1)) + 0.5f) * invSq;
        float refy = ((r >> sh) + 0.5f) * invSq;
        int S = 64 >> lv;
        int start = (lv == 0) ? 0 : (lv == 1) ? 4096 : (lv == 2) ? 5120 : 5376;
        float Sf = (float)S;
        // fused softmax across the 32 lanes of this head (lane bits 0..4)
        float logit = row[512 + head * 32 + lvp];
        float mx = logit;
#pragma unroll
        for (int o = 16; o; o >>= 1) mx = fmaxf(mx, __shfl_xor(mx, o));
        float e = __expf(logit - mx);
        float ssum = e;
#pragma unroll
        for (int o = 16; o; o >>= 1) ssum += __shfl_xor(ssum, o);
        float a = e / ssum;
        float ox = row[head * 64 + lv * 16 + p * 2 + 0];
        float oy = row[head * 64 + lv * 16 + p * 2 + 1];
        float X = refx * Sf + ox - 0.5f;
        float Y = refy * Sf + oy - 0.5f;
        float x0 = floorf(X), y0 = floorf(Y);
        float fx = X - x0, fy = Y - y0;
        int xi0 = (int)x0, yi0 = (int)y0;
        float wv[4]; int iv[4];
#pragma unroll
        for (int tap = 0; tap < 4; ++tap) {
            int dx = tap & 1, dy = tap >> 1;
            int xi = xi0 + dx, yi = yi0 + dy;
            float wgt = (dx ? fx : 1.0f - fx) * (dy ? fy : 1.0f - fy);
            bool valid = (xi >= 0) && (xi < S) && (yi >= 0) && (yi < S);
            int xc = xi < 0 ? 0 : (xi > S - 1 ? S - 1 : xi);
            int yc = yi < 0 ? 0 : (yi > S - 1 ? S - 1 : yi);
            wv[tap] = valid ? wgt * a : 0.0f;
            iv[tap] = start + yc * S + xc;
        }
        *(float4*)&sw[t * 4] = *(float4*)wv;
        *(int4*)&si[t * 4]   = *(int4*)iv;
    }
    __syncthreads();
    int h = t >> 5, qt = (t >> 3) & 3, cg = t & 7;
    const float* vb = val + (size_t)b * L_TOK * D + h * 32 + cg * 4;
    float a0 = 0.f, a1 = 0.f, a2 = 0.f, a3 = 0.f;
    int base = h * 128 + qt * 32;
#pragma unroll
    for (int s = 0; s < 8; ++s) {
#pragma unroll
        for (int tap = 0; tap < 4; ++tap) {
            float wgt = sw[base + s * 4 + tap];
            int   idx = si[base + s * 4 + tap];
            const float4 g = *(const float4*)&vb[(size_t)idx * D];
            a0 += wgt * g.x; a1 += wgt * g.y; a2 += wgt * g.z; a3 += wgt * g.w;
        }
    }
    a0 += __shfl_xor(a0, 8);  a0 += __shfl_xor(a0, 16);
    a1 += __shfl_xor(a1, 8);  a1 += __shfl_xor(a1, 16);
    a2 += __shfl_xor(a2, 8);  a2 += __shfl_xor(a2, 16);
    a3 += __shfl_xor(a3, 8);  a3 += __shfl_xor(a3, 16);
    if (qt == 0) {
        float4 o; o.x = a0; o.y = a1; o.z = a2; o.w = a3;
        *(float4*)&out[(size_t)bl * D + h * 32 + cg * 4] = o;
    }
}

// ---------------- orchestration ----------------
extern "C" void kernel_launch(void* const* d_in, const int* in_sizes, int n_in,
                              void* d_out, int out_size, void* d_ws, size_t ws_size,
                              hipStream_t stream)
{
    const float* s0    = (const float*)d_in[0];
    const float* p0    = (const float*)d_in[1];
    const float* s1    = (const float*)d_in[2];
    const float* p1    = (const float*)d_in[3];
    const float* s2    = (const float*)d_in[4];
    const float* p2    = (const float*)d_in[5];
    const float* s3    = (const float*)d_in[6];
    const float* p3    = (const float*)d_in[7];
    const float* lvl   = (const float*)d_in[8];
    const float* W_off = (const float*)d_in[9];
    const float* b_off = (const float*)d_in[10];
    const float* W_att = (const float*)d_in[11];
    const float* b_att = (const float*)d_in[12];
    const float* W_val = (const float*)d_in[13];
    const float* b_val = (const float*)d_in[14];
    const float* W_out = (const float*)d_in[15];
    const float* b_out = (const float*)d_in[16];
    const float* ln1g  = (const float*)d_in[17];
    const float* ln1b  = (const float*)d_in[18];
    const float* W1    = (const float*)d_in[19];
    const float* b1    = (const float*)d_in[20];
    const float* W2    = (const float*)d_in[21];
    const float* b2    = (const float*)d_in[22];
    const float* ln2g  = (const float*)d_in[23];
    const float* ln2b  = (const float*)d_in[24];

    const size_t S1 = (size_t)NTOK * D;
    float* xbuf = (float*)d_ws;       // persistent x (fp32 residual stream)
    float* pos  = xbuf + S1;          // persistent pos_flat
    float* q    = pos + S1;           // q / x2 / samp (time-shared)
    float* val  = q + S1;             // value projection
    float* big  = val + S1;           // 4*S1: off+attn (ld 768) / ffn hidden (ld 1024)
    short* wt_off = (short*)(big + 4 * S1);         // bf16 transposed weights
    short* wt_att = wt_off + (size_t)6 * 512 * 256;
    short* wt_val = wt_att + (size_t)6 * 256 * 256;
    short* wt_out = wt_val + (size_t)6 * 256 * 256;
    short* wt_1   = wt_out + (size_t)6 * 256 * 256;
    short* wt_2   = wt_1   + (size_t)6 * 1024 * 256;
    float* samp = q;

    // weight prep (bf16, [N][K])
    wconv_kernel<<<dim3(16, 8, 6),  256, 0, stream>>>(W_off, wt_off, 256, 512);
    wconv_kernel<<<dim3(8, 8, 6),   256, 0, stream>>>(W_att, wt_att, 256, 256);
    wconv_kernel<<<dim3(8, 8, 6),   256, 0, stream>>>(W_val, wt_val, 256, 256);
    wconv_kernel<<<dim3(8, 8, 6),   256, 0, stream>>>(W_out, wt_out, 256, 256);
    wconv_kernel<<<dim3(32, 8, 6),  256, 0, stream>>>(W1,    wt_1,   256, 1024);
    wconv_kernel<<<dim3(8, 32, 6),  256, 0, stream>>>(W2,    wt_2,   1024, 256);

    // flatten
    flat_kernel<<<dim3(128, 8, 2), 256, 0, stream>>>(s0, p0, lvl, xbuf, pos, 4096, 0, 0);
    flat_kernel<<<dim3(32, 8, 2),  256, 0, stream>>>(s1, p1, lvl, xbuf, pos, 1024, 4096, 1);
    flat_kernel<<<dim3(8, 8, 2),   256, 0, stream>>>(s2, p2, lvl, xbuf, pos, 256, 5120, 2);
    flat_kernel<<<dim3(2, 8, 2),   256, 0, stream>>>(s3, p3, lvl, xbuf, pos, 64, 5376, 3);

    for (int i = 0; i < 6; ++i) {
        // q = LN1(x) + pos
        ln_kernel<<<NTOK / 4, 256, 0, stream>>>(xbuf, ln1g + i * 256, ln1b + i * 256, pos, q);
        // off = q @ W_off + b_off -> big[:,0:512)
        mm_kernel<<<dim3(4, 85), 256, 0, stream>>>(
            q, wt_off + (size_t)i * 512 * 256, b_off + i * 512, nullptr, big, 512, 256, 768, 0);
        // attn logits -> big[:,512:768)  (softmax fused into sample)
        mm_kernel<<<dim3(2, 85), 256, 0, stream>>>(
            q, wt_att + (size_t)i * 256 * 256, b_att + i * 256, nullptr, big + 512, 256, 256, 768, 0);
        // val = x @ W_val + b_val
        mm_kernel<<<dim3(2, 85), 256, 0, stream>>>(
            xbuf, wt_val + (size_t)i * 256 * 256, b_val + i * 256, nullptr, val, 256, 256, 256, 0);
        // deformable sampling (samp aliases q — q's GEMM consumers are done)
        sample_kernel<<<NTOK, 256, 0, stream>>>(big, val, samp);
        // x = x + samp @ W_out + b_out
        mm_kernel<<<dim3(2, 85), 256, 0, stream>>>(
            samp, wt_out + (size_t)i * 256 * 256, b_out + i * 256, xbuf, xbuf, 256, 256, 256, 0);
        // x2 = LN2(x)
        ln_kernel<<<NTOK / 4, 256, 0, stream>>>(xbuf, ln2g + i * 256, ln2b + i * 256, nullptr, q);
        // h = gelu(x2 @ W1 + b1)
        mm_kernel<<<dim3(8, 85), 256, 0, stream>>>(
            q, wt_1 + (size_t)i * 1024 * 256, b1 + i * 1024, nullptr, big, 1024, 256, 1024, 1);
        // x = x + h @ W2 + b2  (last layer -> d_out)
        float* outp = (i == 5) ? (float*)d_out : xbuf;
        mm_kernel<<<dim3(2, 85), 256, 0, stream>>>(
            big, wt_2 + (size_t)i * 256 * 1024, b2 + i * 256, xbuf, outp, 256, 1024, 256, 0);
    }
}

// Round 5
// 1019.563 us; speedup vs baseline: 3.0141x; 1.2322x over previous
//
#include <hip/hip_runtime.h>
#include <hip/hip_bf16.h>
#include <math.h>

#define L_TOK 5440
#define NTOK  10880   // B * L
#define D     256

typedef __attribute__((ext_vector_type(8))) short short8;
typedef __attribute__((ext_vector_type(4))) short short4v;
typedef __attribute__((ext_vector_type(4))) float f32x4;

__device__ __forceinline__ short f2bf(float f) {
    __hip_bfloat16 h = __float2bfloat16(f);
    return __builtin_bit_cast(short, h);
}
__device__ __forceinline__ float bf2f(short s) {
    unsigned u = ((unsigned)(unsigned short)s) << 16;
    return __builtin_bit_cast(float, u);
}

// ---------------- flatten via LDS transpose: (B,d,H,W) -> (B,L,d) f32 + bf16, pos += level_embed
__global__ __launch_bounds__(256) void flat_kernel(
    const float* __restrict__ s, const float* __restrict__ p, const float* __restrict__ le,
    float* __restrict__ x, short* __restrict__ xb, float* __restrict__ pos,
    int HW, int start, int lv)
{
    __shared__ float ts[32][33], tp[32][33];
    int b = blockIdx.z, c0 = blockIdx.y * 32, pix0 = blockIdx.x * 32;
    int tx = threadIdx.x & 31, ty = threadIdx.x >> 5;
#pragma unroll
    for (int i = 0; i < 4; ++i) {
        int c = c0 + ty + i * 8;
        size_t gi = ((size_t)b * D + c) * HW + pix0 + tx;
        ts[ty + i * 8][tx] = s[gi];
        tp[ty + i * 8][tx] = p[gi];
    }
    __syncthreads();
#pragma unroll
    for (int i = 0; i < 4; ++i) {
        int pix = pix0 + ty + i * 8;
        size_t bl = (size_t)b * L_TOK + start + pix;
        int c = c0 + tx;
        float v = ts[tx][ty + i * 8];
        x[bl * D + c]   = v;
        xb[bl * D + c]  = f2bf(v);
        pos[bl * D + c] = tp[tx][ty + i * 8] + le[lv * D + c];
    }
}

// ---------------- weight convert+transpose: W (depth,K,N) f32 -> Wt (depth, rowoff+N, K) bf16 ----
__global__ __launch_bounds__(256) void wconv_kernel(
    const float* __restrict__ W, short* __restrict__ Wt, int K, int N,
    int dstride, int rowoff)
{
    __shared__ float tile[32][33];
    int d = blockIdx.z;
    int n0 = blockIdx.x * 32, k0 = blockIdx.y * 32;
    const float* Wd = W + (size_t)d * K * N;
    short* Wtd = Wt + (size_t)d * dstride + (size_t)rowoff * K;
    int tx = threadIdx.x & 31, ty = threadIdx.x >> 5;
#pragma unroll
    for (int i = 0; i < 4; ++i)
        tile[ty + i * 8][tx] = Wd[(size_t)(k0 + ty + i * 8) * N + n0 + tx];
    __syncthreads();
#pragma unroll
    for (int i = 0; i < 4; ++i)
        Wtd[(size_t)(n0 + ty + i * 8) * K + k0 + tx] = f2bf(tile[tx][ty + i * 8]);
}

// ---------------- pack b_off(512) ++ b_att(256) -> bqa(768) per depth ----------------
__global__ __launch_bounds__(256) void bpack_kernel(
    const float* __restrict__ boff, const float* __restrict__ batt, float* __restrict__ bqa)
{
    int i = blockIdx.x * 256 + threadIdx.x;
    if (i >= 6 * 768) return;
    int d = i / 768, c = i - d * 768;
    bqa[i] = (c < 512) ? boff[d * 512 + c] : batt[d * 256 + c - 512];
}

// ---------------- LayerNorm -> bf16 (one wave per token) ----------------
__global__ __launch_bounds__(256) void ln_kernel(
    const float* __restrict__ x, const float* __restrict__ g, const float* __restrict__ bta,
    const float* __restrict__ pos, short* __restrict__ out)
{
    int wid = threadIdx.x >> 6, lane = threadIdx.x & 63;
    int m = blockIdx.x * 4 + wid;
    const float* xr = x + (size_t)m * D;
    float v[4];
#pragma unroll
    for (int i = 0; i < 4; ++i) v[i] = xr[lane + i * 64];
    float s = v[0] + v[1] + v[2] + v[3];
#pragma unroll
    for (int o = 32; o; o >>= 1) s += __shfl_xor(s, o);
    float mean = s * (1.0f / D);
    float sq = 0.0f;
#pragma unroll
    for (int i = 0; i < 4; ++i) { float d = v[i] - mean; sq += d * d; }
#pragma unroll
    for (int o = 32; o; o >>= 1) sq += __shfl_xor(sq, o);
    float rstd = rsqrtf(sq * (1.0f / D) + 1e-5f);
    short* orow = out + (size_t)m * D;
#pragma unroll
    for (int i = 0; i < 4; ++i) {
        int c = lane + i * 64;
        float o = (v[i] - mean) * rstd * g[c] + bta[c];
        if (pos) o += pos[(size_t)m * D + c];
        orow[c] = f2bf(o);
    }
}

// ---------------- bf16 MFMA GEMM body: out = act(A[M,K] @ Wt[N,K]^T + bias) (+resid) ----------
// 128x128 tile, BK=32, 4 waves (2x2), wave 64x64 via 4x4 mfma_16x16x32.
// LDS [128][32] bf16; XOR swizzle byte ^= (((row>>1)&3)<<4) (bijective in 64B row,
// fragment reads collide only r/r+8 -> 2-way = free).
__device__ __forceinline__ void mm_body(
    const short* __restrict__ A, const short* __restrict__ Wt,
    const float* __restrict__ bias, const float* __restrict__ resid,
    float* __restrict__ Cf, short* __restrict__ Cb,
    int row0, int col0, int K, int ldc, int act)
{
    __shared__ short As[128 * 32];
    __shared__ short Bs[128 * 32];
    int tid = threadIdx.x;
    int lane = tid & 63, w = tid >> 6;
    int wr = w >> 1, wc = w & 1;
    int l15 = lane & 15, l16 = lane >> 4;

    int a_off[4], b_off[4];
#pragma unroll
    for (int m = 0; m < 4; ++m) {
        int ra = wr * 64 + m * 16 + l15;
        a_off[m] = ra * 32 + ((((l16 * 16)) ^ (((ra >> 1) & 3) << 4)) >> 1);
        int rb = wc * 64 + m * 16 + l15;
        b_off[m] = rb * 32 + ((((l16 * 16)) ^ (((rb >> 1) & 3) << 4)) >> 1);
    }
    int sr = tid >> 2, skb = (tid & 3) * 8;

    f32x4 acc[4][4];
#pragma unroll
    for (int m = 0; m < 4; ++m)
#pragma unroll
        for (int n = 0; n < 4; ++n) acc[m][n] = (f32x4){0.f, 0.f, 0.f, 0.f};

    for (int k0 = 0; k0 < K; k0 += 32) {
#pragma unroll
        for (int it = 0; it < 2; ++it) {
            int r = sr + it * 64;
            int soff = r * 32 + ((((skb * 2)) ^ (((r >> 1) & 3) << 4)) >> 1);
            *(short8*)&As[soff] = *(const short8*)&A[(size_t)(row0 + r) * K + k0 + skb];
            *(short8*)&Bs[soff] = *(const short8*)&Wt[(size_t)(col0 + r) * K + k0 + skb];
        }
        __syncthreads();
        short8 af[4], bfr[4];
#pragma unroll
        for (int m = 0; m < 4; ++m) af[m] = *(short8*)&As[a_off[m]];
#pragma unroll
        for (int n = 0; n < 4; ++n) bfr[n] = *(short8*)&Bs[b_off[n]];
#pragma unroll
        for (int m = 0; m < 4; ++m)
#pragma unroll
            for (int n = 0; n < 4; ++n)
                acc[m][n] = __builtin_amdgcn_mfma_f32_16x16x32_bf16(af[m], bfr[n], acc[m][n], 0, 0, 0);
        __syncthreads();
    }

#pragma unroll
    for (int m = 0; m < 4; ++m) {
#pragma unroll
        for (int j = 0; j < 4; ++j) {
            int row = row0 + wr * 64 + m * 16 + l16 * 4 + j;
#pragma unroll
            for (int n = 0; n < 4; ++n) {
                int col = col0 + wc * 64 + n * 16 + l15;
                float v = acc[m][n][j] + bias[col];
                if (act) v = 0.5f * v * (1.0f + erff(v * 0.70710678118654752f));
                if (resid) v += resid[(size_t)row * ldc + col];
                if (Cf) Cf[(size_t)row * ldc + col] = v;
                if (Cb) Cb[(size_t)row * ldc + col] = f2bf(v);
            }
        }
    }
}

__global__ __launch_bounds__(256) void mm_kernel(
    const short* __restrict__ A, const short* __restrict__ Wt,
    const float* __restrict__ bias, const float* __restrict__ resid,
    float* __restrict__ Cf, short* __restrict__ Cb, int K, int ldc, int act)
{
    mm_body(A, Wt, bias, resid, Cf, Cb, blockIdx.y * 128, blockIdx.x * 128, K, ldc, act);
}

// two independent GEMMs (shared M, K) in one launch: x-blocks [0,nx1) -> #1, rest -> #2
__global__ __launch_bounds__(256) void mm2_kernel(
    const short* __restrict__ A1, const short* __restrict__ Wt1, const float* __restrict__ bias1,
    float* __restrict__ Cf1, int ldc1,
    const short* __restrict__ A2, const short* __restrict__ Wt2, const float* __restrict__ bias2,
    short* __restrict__ Cb2, int ldc2,
    int nx1, int K)
{
    const short *A, *Wt; const float* bias; float* Cf; short* Cb; int ldc, col0;
    if ((int)blockIdx.x < nx1) {
        A = A1; Wt = Wt1; bias = bias1; Cf = Cf1; Cb = nullptr; ldc = ldc1;
        col0 = blockIdx.x * 128;
    } else {
        A = A2; Wt = Wt2; bias = bias2; Cf = nullptr; Cb = Cb2; ldc = ldc2;
        col0 = (blockIdx.x - nx1) * 128;
    }
    mm_body(A, Wt, bias, nullptr, Cf, Cb, blockIdx.y * 128, col0, K, ldc, 0);
}

// ---------------- deformable sampling (softmax fused, bf16 val, bf16 out) ----------------
// big row: [0:512) = off (h,lv,p,2) f32, [512:768) = attn logits (h, lv*8+p) f32
// LDS layout sw/si[h*132 + qt*33 + s*4 + tap]: phase-2 read banks = (h*4+qt+s*4+tap)%32,
// the wave's 8 (h,qt) groups land on 8 distinct banks -> conflict-free.
__global__ __launch_bounds__(256) void sample_kernel(
    const float* __restrict__ big, const short* __restrict__ val, short* __restrict__ out)
{
    __shared__ float sw[8 * 132];
    __shared__ int   si[8 * 132];
    int bl = blockIdx.x;
    int b = bl / L_TOK, l = bl - b * L_TOK;
    const float* row = big + (size_t)bl * 768;
    int t = threadIdx.x;
    {
        int head = t >> 5, lvp = t & 31, lv = lvp >> 3, p = lvp & 7;
        int lq, r;
        if (l < 4096)      { lq = 0; r = l;        }
        else if (l < 5120) { lq = 1; r = l - 4096; }
        else if (l < 5376) { lq = 2; r = l - 5120; }
        else               { lq = 3; r = l - 5376; }
        int sh = 6 - lq;
        float invSq = 1.0f / (float)(1 << sh);
        float refx = ((r & ((1 << sh) - 1)) + 0.5f) * invSq;
        float refy = ((r >> sh) + 0.5f) * invSq;
        int S = 64 >> lv;
        int start = (lv == 0) ? 0 : (lv == 1) ? 4096 : (lv == 2) ? 5120 : 5376;
        float Sf = (float)S;
        // softmax across the 32 lanes of this head
        float logit = row[512 + head * 32 + lvp];
        float mx = logit;
#pragma unroll
        for (int o = 16; o; o >>= 1) mx = fmaxf(mx, __shfl_xor(mx, o));
        float e = __expf(logit - mx);
        float ssum = e;
#pragma unroll
        for (int o = 16; o; o >>= 1) ssum += __shfl_xor(ssum, o);
        float a = e / ssum;
        float ox = row[head * 64 + lv * 16 + p * 2 + 0];
        float oy = row[head * 64 + lv * 16 + p * 2 + 1];
        float X = refx * Sf + ox - 0.5f;
        float Y = refy * Sf + oy - 0.5f;
        float x0 = floorf(X), y0 = floorf(Y);
        float fx = X - x0, fy = Y - y0;
        int xi0 = (int)x0, yi0 = (int)y0;
        int qt = lvp >> 3, s = lvp & 7;
        int base_w = head * 132 + qt * 33 + s * 4;
#pragma unroll
        for (int tap = 0; tap < 4; ++tap) {
            int dx = tap & 1, dy = tap >> 1;
            int xi = xi0 + dx, yi = yi0 + dy;
            float wgt = (dx ? fx : 1.0f - fx) * (dy ? fy : 1.0f - fy);
            bool valid = (xi >= 0) && (xi < S) && (yi >= 0) && (yi < S);
            int xc = xi < 0 ? 0 : (xi > S - 1 ? S - 1 : xi);
            int yc = yi < 0 ? 0 : (yi > S - 1 ? S - 1 : yi);
            sw[base_w + tap] = valid ? wgt * a : 0.0f;
            si[base_w + tap] = start + yc * S + xc;
        }
    }
    __syncthreads();
    int h = t >> 5, qt = (t >> 3) & 3, cg = t & 7;
    const short* vb = val + (size_t)b * L_TOK * D + h * 32 + cg * 4;
    float a0 = 0.f, a1 = 0.f, a2 = 0.f, a3 = 0.f;
    int base = h * 132 + qt * 33;
#pragma unroll
    for (int s = 0; s < 8; ++s) {
#pragma unroll
        for (int tap = 0; tap < 4; ++tap) {
            float wgt = sw[base + s * 4 + tap];
            int   idx = si[base + s * 4 + tap];
            const short4v g = *(const short4v*)&vb[(size_t)idx * D];
            a0 += wgt * bf2f(g[0]); a1 += wgt * bf2f(g[1]);
            a2 += wgt * bf2f(g[2]); a3 += wgt * bf2f(g[3]);
        }
    }
    a0 += __shfl_xor(a0, 8);  a0 += __shfl_xor(a0, 16);
    a1 += __shfl_xor(a1, 8);  a1 += __shfl_xor(a1, 16);
    a2 += __shfl_xor(a2, 8);  a2 += __shfl_xor(a2, 16);
    a3 += __shfl_xor(a3, 8);  a3 += __shfl_xor(a3, 16);
    if (qt == 0) {
        short4v o;
        o[0] = f2bf(a0); o[1] = f2bf(a1); o[2] = f2bf(a2); o[3] = f2bf(a3);
        *(short4v*)&out[(size_t)bl * D + h * 32 + cg * 4] = o;
    }
}

// ---------------- orchestration ----------------
extern "C" void kernel_launch(void* const* d_in, const int* in_sizes, int n_in,
                              void* d_out, int out_size, void* d_ws, size_t ws_size,
                              hipStream_t stream)
{
    const float* s0    = (const float*)d_in[0];
    const float* p0    = (const float*)d_in[1];
    const float* s1    = (const float*)d_in[2];
    const float* p1    = (const float*)d_in[3];
    const float* s2    = (const float*)d_in[4];
    const float* p2    = (const float*)d_in[5];
    const float* s3    = (const float*)d_in[6];
    const float* p3    = (const float*)d_in[7];
    const float* lvl   = (const float*)d_in[8];
    const float* W_off = (const float*)d_in[9];
    const float* b_off = (const float*)d_in[10];
    const float* W_att = (const float*)d_in[11];
    const float* b_att = (const float*)d_in[12];
    const float* W_val = (const float*)d_in[13];
    const float* b_val = (const float*)d_in[14];
    const float* W_out = (const float*)d_in[15];
    const float* b_out = (const float*)d_in[16];
    const float* ln1g  = (const float*)d_in[17];
    const float* ln1b  = (const float*)d_in[18];
    const float* W1    = (const float*)d_in[19];
    const float* b1    = (const float*)d_in[20];
    const float* W2    = (const float*)d_in[21];
    const float* b2    = (const float*)d_in[22];
    const float* ln2g  = (const float*)d_in[23];
    const float* ln2b  = (const float*)d_in[24];

    const size_t S1 = (size_t)NTOK * D;
    // fp32 region
    float* xbuf = (float*)d_ws;       // S1  : residual stream
    float* pos  = xbuf + S1;          // S1
    float* big  = pos + S1;           // 3*S1: off+attn (ld 768)
    float* bqa  = big + 3 * S1;       // 6*768: packed off/attn bias
    // bf16 region
    short* qbf   = (short*)(bqa + 6 * 768);        // S1 : LN1(x)+pos / LN2(x)
    short* x_bf  = qbf + S1;                       // S1 : bf16 of residual x
    short* valbf = x_bf + S1;                      // S1
    short* sampb = valbf + S1;                     // S1
    short* hidbf = sampb + S1;                     // 4*S1 : FFN hidden
    short* wt_qa  = hidbf + 4 * S1;                // [6][768][256]
    short* wt_val = wt_qa  + (size_t)6 * 768 * 256;
    short* wt_out = wt_val + (size_t)6 * 256 * 256;
    short* wt_1   = wt_out + (size_t)6 * 256 * 256;
    short* wt_2   = wt_1   + (size_t)6 * 1024 * 256;

    // weight prep (bf16 [N][K]); off+attn packed to 768 rows
    wconv_kernel<<<dim3(16, 8, 6), 256, 0, stream>>>(W_off, wt_qa, 256, 512, 768 * 256, 0);
    wconv_kernel<<<dim3(8, 8, 6),  256, 0, stream>>>(W_att, wt_qa, 256, 256, 768 * 256, 512);
    wconv_kernel<<<dim3(8, 8, 6),  256, 0, stream>>>(W_val, wt_val, 256, 256, 256 * 256, 0);
    wconv_kernel<<<dim3(8, 8, 6),  256, 0, stream>>>(W_out, wt_out, 256, 256, 256 * 256, 0);
    wconv_kernel<<<dim3(32, 8, 6), 256, 0, stream>>>(W1,    wt_1,   256, 1024, 1024 * 256, 0);
    wconv_kernel<<<dim3(8, 32, 6), 256, 0, stream>>>(W2,    wt_2,   1024, 256, 256 * 1024, 0);
    bpack_kernel<<<18, 256, 0, stream>>>(b_off, b_att, bqa);

    // flatten
    flat_kernel<<<dim3(128, 8, 2), 256, 0, stream>>>(s0, p0, lvl, xbuf, x_bf, pos, 4096, 0, 0);
    flat_kernel<<<dim3(32, 8, 2),  256, 0, stream>>>(s1, p1, lvl, xbuf, x_bf, pos, 1024, 4096, 1);
    flat_kernel<<<dim3(8, 8, 2),   256, 0, stream>>>(s2, p2, lvl, xbuf, x_bf, pos, 256, 5120, 2);
    flat_kernel<<<dim3(2, 8, 2),   256, 0, stream>>>(s3, p3, lvl, xbuf, x_bf, pos, 64, 5376, 3);

    for (int i = 0; i < 6; ++i) {
        // q = LN1(x) + pos  (bf16)
        ln_kernel<<<NTOK / 4, 256, 0, stream>>>(xbuf, ln1g + i * 256, ln1b + i * 256, pos, qbf);
        // fused: [off|attn] = q @ Wqa -> big (f32, ld 768)  ||  val = x @ W_val -> valbf (bf16)
        mm2_kernel<<<dim3(8, 85), 256, 0, stream>>>(
            qbf, wt_qa + (size_t)i * 768 * 256, bqa + i * 768, big, 768,
            x_bf, wt_val + (size_t)i * 256 * 256, b_val + i * 256, valbf, 256,
            6, 256);
        // deformable sampling
        sample_kernel<<<NTOK, 256, 0, stream>>>(big, valbf, sampb);
        // x = x + samp @ W_out + b_out  (f32)
        mm_kernel<<<dim3(2, 85), 256, 0, stream>>>(
            sampb, wt_out + (size_t)i * 256 * 256, b_out + i * 256, xbuf, xbuf, nullptr, 256, 256, 0);
        // x2 = LN2(x) (bf16)
        ln_kernel<<<NTOK / 4, 256, 0, stream>>>(xbuf, ln2g + i * 256, ln2b + i * 256, nullptr, qbf);
        // h = gelu(x2 @ W1 + b1)  (bf16)
        mm_kernel<<<dim3(8, 85), 256, 0, stream>>>(
            qbf, wt_1 + (size_t)i * 1024 * 256, b1 + i * 1024, nullptr, nullptr, hidbf, 256, 1024, 1);
        // x = x + h @ W2 + b2  (f32; last layer -> d_out; also refresh x_bf for next val GEMM)
        float* outp = (i == 5) ? (float*)d_out : xbuf;
        short* xbp  = (i == 5) ? nullptr : x_bf;
        mm_kernel<<<dim3(2, 85), 256, 0, stream>>>(
            hidbf, wt_2 + (size_t)i * 256 * 1024, b2 + i * 256, xbuf, outp, xbp, 1024, 256, 0);
    }
}

// Round 8
// 921.438 us; speedup vs baseline: 3.3350x; 1.1065x over previous
//
#include <hip/hip_runtime.h>
#include <hip/hip_bf16.h>
#include <math.h>

#define L_TOK 5440
#define NTOK  10880   // B * L
#define D     256

typedef __attribute__((ext_vector_type(8))) short short8;
typedef __attribute__((ext_vector_type(4))) short short4v;
typedef __attribute__((ext_vector_type(4))) float f32x4;

__device__ __forceinline__ short f2bf(float f) {
    __hip_bfloat16 h = __float2bfloat16(f);
    return __builtin_bit_cast(short, h);
}
__device__ __forceinline__ float bf2f(short s) {
    unsigned u = ((unsigned)(unsigned short)s) << 16;
    return __builtin_bit_cast(float, u);
}

#define GLL16(gp, lp) \
    __builtin_amdgcn_global_load_lds((const __attribute__((address_space(1))) void*)(gp), \
                                     (__attribute__((address_space(3))) void*)(lp), 16, 0, 0)

// ---------------- flatten via LDS transpose: (B,d,H,W) -> (B,L,d) f32 + bf16, pos += level_embed
__global__ __launch_bounds__(256) void flat_kernel(
    const float* __restrict__ s, const float* __restrict__ p, const float* __restrict__ le,
    float* __restrict__ x, short* __restrict__ xb, float* __restrict__ pos,
    int HW, int start, int lv)
{
    __shared__ float ts[32][33], tp[32][33];
    int b = blockIdx.z, c0 = blockIdx.y * 32, pix0 = blockIdx.x * 32;
    int tx = threadIdx.x & 31, ty = threadIdx.x >> 5;
#pragma unroll
    for (int i = 0; i < 4; ++i) {
        int c = c0 + ty + i * 8;
        size_t gi = ((size_t)b * D + c) * HW + pix0 + tx;
        ts[ty + i * 8][tx] = s[gi];
        tp[ty + i * 8][tx] = p[gi];
    }
    __syncthreads();
#pragma unroll
    for (int i = 0; i < 4; ++i) {
        int pix = pix0 + ty + i * 8;
        size_t bl = (size_t)b * L_TOK + start + pix;
        int c = c0 + tx;
        float v = ts[tx][ty + i * 8];
        x[bl * D + c]   = v;
        xb[bl * D + c]  = f2bf(v);
        pos[bl * D + c] = tp[tx][ty + i * 8] + le[lv * D + c];
    }
}

// ---------------- weight convert+transpose: W (depth,K,N) f32 -> Wt (depth, rowoff+N, K) bf16 ----
__global__ __launch_bounds__(256) void wconv_kernel(
    const float* __restrict__ W, short* __restrict__ Wt, int K, int N,
    int dstride, int rowoff)
{
    __shared__ float tile[32][33];
    int d = blockIdx.z;
    int n0 = blockIdx.x * 32, k0 = blockIdx.y * 32;
    const float* Wd = W + (size_t)d * K * N;
    short* Wtd = Wt + (size_t)d * dstride + (size_t)rowoff * K;
    int tx = threadIdx.x & 31, ty = threadIdx.x >> 5;
#pragma unroll
    for (int i = 0; i < 4; ++i)
        tile[ty + i * 8][tx] = Wd[(size_t)(k0 + ty + i * 8) * N + n0 + tx];
    __syncthreads();
#pragma unroll
    for (int i = 0; i < 4; ++i)
        Wtd[(size_t)(n0 + ty + i * 8) * K + k0 + tx] = f2bf(tile[tx][ty + i * 8]);
}

// ---------------- pack b_off(512) ++ b_att(256) -> bqa(768) per depth ----------------
__global__ __launch_bounds__(256) void bpack_kernel(
    const float* __restrict__ boff, const float* __restrict__ batt, float* __restrict__ bqa)
{
    int i = blockIdx.x * 256 + threadIdx.x;
    if (i >= 6 * 768) return;
    int d = i / 768, c = i - d * 768;
    bqa[i] = (c < 512) ? boff[d * 512 + c] : batt[d * 256 + c - 512];
}

// ---------------- LayerNorm -> bf16 (one wave per token) ----------------
__global__ __launch_bounds__(256) void ln_kernel(
    const float* __restrict__ x, const float* __restrict__ g, const float* __restrict__ bta,
    const float* __restrict__ pos, short* __restrict__ out)
{
    int wid = threadIdx.x >> 6, lane = threadIdx.x & 63;
    int m = blockIdx.x * 4 + wid;
    const float* xr = x + (size_t)m * D;
    float v[4];
#pragma unroll
    for (int i = 0; i < 4; ++i) v[i] = xr[lane + i * 64];
    float s = v[0] + v[1] + v[2] + v[3];
#pragma unroll
    for (int o = 32; o; o >>= 1) s += __shfl_xor(s, o);
    float mean = s * (1.0f / D);
    float sq = 0.0f;
#pragma unroll
    for (int i = 0; i < 4; ++i) { float d = v[i] - mean; sq += d * d; }
#pragma unroll
    for (int o = 32; o; o >>= 1) sq += __shfl_xor(sq, o);
    float rstd = rsqrtf(sq * (1.0f / D) + 1e-5f);
    short* orow = out + (size_t)m * D;
#pragma unroll
    for (int i = 0; i < 4; ++i) {
        int c = lane + i * 64;
        float o = (v[i] - mean) * rstd * g[c] + bta[c];
        if (pos) o += pos[(size_t)m * D + c];
        orow[c] = f2bf(o);
    }
}

// ---------------- bf16 MFMA GEMM body: out = act(A[M,K] @ Wt[N,K]^T + bias) (+resid) ----------
// 128x128 tile, BK=64, 4 waves (2x2), wave 64x64 via 4x4 mfma_16x16x32.
// Staging: global_load_lds width-16, LDS LINEAR [128][64]; the bank-conflict swizzle
// (slot ^= row&7, slots = 16B units of the 128B row) is applied on the GLOBAL source
// address (rule #21: linear dest + inverse-swizzled source + swizzled ds_read).
// Fragment ds_read_b128: lanes 0..15 read rows r=0..15 at slot kk*4+l16 ^ (r&7) ->
// each bank-group hit by exactly 2 rows (r, r+8) -> 2-way = free.
__device__ __forceinline__ void mm_body(
    const short* __restrict__ A, const short* __restrict__ Wt,
    const float* __restrict__ bias, const float* __restrict__ resid,
    float* __restrict__ Cf, short* __restrict__ Cb,
    int row0, int col0, int K, int ldc, int act)
{
    __shared__ __align__(16) short As[128 * 64];
    __shared__ __align__(16) short Bs[128 * 64];
    int tid = threadIdx.x;
    int lane = tid & 63, w = tid >> 6;
    int wr = w >> 1, wc = w & 1;
    int l15 = lane & 15, l16 = lane >> 4;

    // fragment LDS offsets (shorts): row*64 + swizzled-slot*8
    int a_off[4][2], b_off[4][2];
#pragma unroll
    for (int m = 0; m < 4; ++m) {
#pragma unroll
        for (int kk = 0; kk < 2; ++kk) {
            int ra = wr * 64 + m * 16 + l15;
            a_off[m][kk] = ra * 64 + (((kk * 4 + l16) ^ (ra & 7)) << 3);
            int rb = wc * 64 + m * 16 + l15;
            b_off[m][kk] = rb * 64 + (((kk * 4 + l16) ^ (rb & 7)) << 3);
        }
    }

    // staging: wave w covers rows [w*32, w*32+32), chunk c = 8 rows (1 KB).
    // lane l -> row w*32 + c*8 + (l>>3), LDS slot l&7, global slot (l&7)^((l>>3)&7).
    int sg = (lane & 7) ^ ((lane >> 3) & 7);
    const short* ag = A  + (size_t)(row0 + w * 32 + (lane >> 3)) * K + sg * 8;
    const short* bg = Wt + (size_t)(col0 + w * 32 + (lane >> 3)) * K + sg * 8;

    f32x4 acc[4][4];
#pragma unroll
    for (int m = 0; m < 4; ++m)
#pragma unroll
        for (int n = 0; n < 4; ++n) acc[m][n] = (f32x4){0.f, 0.f, 0.f, 0.f};

    for (int k0 = 0; k0 < K; k0 += 64) {
#pragma unroll
        for (int c = 0; c < 4; ++c) {
            GLL16(ag + (size_t)c * 8 * K + k0, &As[w * 2048 + c * 512]);
            GLL16(bg + (size_t)c * 8 * K + k0, &Bs[w * 2048 + c * 512]);
        }
        __syncthreads();
#pragma unroll
        for (int kk = 0; kk < 2; ++kk) {
            short8 af[4], bfr[4];
#pragma unroll
            for (int m = 0; m < 4; ++m) af[m] = *(short8*)&As[a_off[m][kk]];
#pragma unroll
            for (int n = 0; n < 4; ++n) bfr[n] = *(short8*)&Bs[b_off[n][kk]];
#pragma unroll
            for (int m = 0; m < 4; ++m)
#pragma unroll
                for (int n = 0; n < 4; ++n)
                    acc[m][n] = __builtin_amdgcn_mfma_f32_16x16x32_bf16(af[m], bfr[n], acc[m][n], 0, 0, 0);
        }
        __syncthreads();
    }

#pragma unroll
    for (int m = 0; m < 4; ++m) {
#pragma unroll
        for (int j = 0; j < 4; ++j) {
            int row = row0 + wr * 64 + m * 16 + l16 * 4 + j;
#pragma unroll
            for (int n = 0; n < 4; ++n) {
                int col = col0 + wc * 64 + n * 16 + l15;
                float v = acc[m][n][j] + bias[col];
                if (act) v = 0.5f * v * (1.0f + erff(v * 0.70710678118654752f));
                if (resid) v += resid[(size_t)row * ldc + col];
                if (Cf) Cf[(size_t)row * ldc + col] = v;
                if (Cb) Cb[(size_t)row * ldc + col] = f2bf(v);
            }
        }
    }
}

__global__ __launch_bounds__(256) void mm_kernel(
    const short* __restrict__ A, const short* __restrict__ Wt,
    const float* __restrict__ bias, const float* __restrict__ resid,
    float* __restrict__ Cf, short* __restrict__ Cb, int K, int ldc, int act)
{
    mm_body(A, Wt, bias, resid, Cf, Cb, blockIdx.y * 128, blockIdx.x * 128, K, ldc, act);
}

// two independent GEMMs (shared M, K) in one launch: x-blocks [0,nx1) -> #1, rest -> #2
__global__ __launch_bounds__(256) void mm2_kernel(
    const short* __restrict__ A1, const short* __restrict__ Wt1, const float* __restrict__ bias1,
    float* __restrict__ Cf1, int ldc1,
    const short* __restrict__ A2, const short* __restrict__ Wt2, const float* __restrict__ bias2,
    short* __restrict__ Cb2, int ldc2,
    int nx1, int K)
{
    const short *A, *Wt; const float* bias; float* Cf; short* Cb; int ldc, col0;
    if ((int)blockIdx.x < nx1) {
        A = A1; Wt = Wt1; bias = bias1; Cf = Cf1; Cb = nullptr; ldc = ldc1;
        col0 = blockIdx.x * 128;
    } else {
        A = A2; Wt = Wt2; bias = bias2; Cf = nullptr; Cb = Cb2; ldc = ldc2;
        col0 = (blockIdx.x - nx1) * 128;
    }
    mm_body(A, Wt, bias, nullptr, Cf, Cb, blockIdx.y * 128, col0, K, ldc, 0);
}

// ---------------- deformable sampling (softmax fused, bf16 val, 16B gathers) ----------------
// big row: [0:512) = off (h,lv,p,2) f32, [512:768) = attn logits (h, lv*8+p) f32
// LDS sw/si[h*132 + qt*33 + s*4 + tap] (qt = s>>3): padded strides keep reads <=2-way.
// phase2: t = h*32 + sgp*4 + cg ; 8 channels (cg*8) x 4 samples {sgp, sgp+8, sgp+16, sgp+24}
//         x 4 taps = 16 short8 gathers; shfl-reduce over sgp (strides 4,8,16).
__global__ __launch_bounds__(256) void sample_kernel(
    const float* __restrict__ big, const short* __restrict__ val, short* __restrict__ out)
{
    __shared__ float sw[8 * 132];
    __shared__ int   si[8 * 132];
    int bl = blockIdx.x;
    int b = bl / L_TOK, l = bl - b * L_TOK;
    const float* row = big + (size_t)bl * 768;
    int t = threadIdx.x;
    {
        int head = t >> 5, lvp = t & 31, lv = lvp >> 3, p = lvp & 7;
        int lq, r;
        if (l < 4096)      { lq = 0; r = l;        }
        else if (l < 5120) { lq = 1; r = l - 4096; }
        else if (l < 5376) { lq = 2; r = l - 5120; }
        else               { lq = 3; r = l - 5376; }
        int sh = 6 - lq;
        float invSq = 1.0f / (float)(1 << sh);
        float refx = ((r & ((1 << sh) - 1)) + 0.5f) * invSq;
        float refy = ((r >> sh) + 0.5f) * invSq;
        int S = 64 >> lv;
        int start = (lv == 0) ? 0 : (lv == 1) ? 4096 : (lv == 2) ? 5120 : 5376;
        float Sf = (float)S;
        // softmax across the 32 lanes of this head
        float logit = row[512 + head * 32 + lvp];
        float mx = logit;
#pragma unroll
        for (int o = 16; o; o >>= 1) mx = fmaxf(mx, __shfl_xor(mx, o));
        float e = __expf(logit - mx);
        float ssum = e;
#pragma unroll
        for (int o = 16; o; o >>= 1) ssum += __shfl_xor(ssum, o);
        float a = e / ssum;
        float ox = row[head * 64 + lv * 16 + p * 2 + 0];
        float oy = row[head * 64 + lv * 16 + p * 2 + 1];
        float X = refx * Sf + ox - 0.5f;
        float Y = refy * Sf + oy - 0.5f;
        float x0 = floorf(X), y0 = floorf(Y);
        float fx = X - x0, fy = Y - y0;
        int xi0 = (int)x0, yi0 = (int)y0;
        int qt = lvp >> 3, sidx = lvp & 7;
        int base_w = head * 132 + qt * 33 + sidx * 4;
#pragma unroll
        for (int tap = 0; tap < 4; ++tap) {
            int dx = tap & 1, dy = tap >> 1;
            int xi = xi0 + dx, yi = yi0 + dy;
            float wgt = (dx ? fx : 1.0f - fx) * (dy ? fy : 1.0f - fy);
            bool valid = (xi >= 0) && (xi < S) && (yi >= 0) && (yi < S);
            int xc = xi < 0 ? 0 : (xi > S - 1 ? S - 1 : xi);
            int yc = yi < 0 ? 0 : (yi > S - 1 ? S - 1 : yi);
            sw[base_w + tap] = valid ? wgt * a : 0.0f;
            si[base_w + tap] = start + yc * S + xc;
        }
    }
    __syncthreads();
    int h = t >> 5, sgp = (t >> 2) & 7, cg = t & 3;
    const short* vb = val + (size_t)b * L_TOK * D + h * 32 + cg * 8;
    float a0 = 0.f, a1 = 0.f, a2 = 0.f, a3 = 0.f;
    float a4 = 0.f, a5 = 0.f, a6 = 0.f, a7 = 0.f;
#pragma unroll
    for (int ss = 0; ss < 4; ++ss) {
        int base = h * 132 + ss * 33 + sgp * 4;
#pragma unroll
        for (int tap = 0; tap < 4; ++tap) {
            float wgt = sw[base + tap];
            int   idx = si[base + tap];
            const short8 g = *(const short8*)&vb[(size_t)idx * D];
            a0 += wgt * bf2f(g[0]); a1 += wgt * bf2f(g[1]);
            a2 += wgt * bf2f(g[2]); a3 += wgt * bf2f(g[3]);
            a4 += wgt * bf2f(g[4]); a5 += wgt * bf2f(g[5]);
            a6 += wgt * bf2f(g[6]); a7 += wgt * bf2f(g[7]);
        }
    }
#pragma unroll
    for (int o = 4; o <= 16; o <<= 1) {
        a0 += __shfl_xor(a0, o); a1 += __shfl_xor(a1, o);
        a2 += __shfl_xor(a2, o); a3 += __shfl_xor(a3, o);
        a4 += __shfl_xor(a4, o); a5 += __shfl_xor(a5, o);
        a6 += __shfl_xor(a6, o); a7 += __shfl_xor(a7, o);
    }
    if (sgp == 0) {
        short8 o;
        o[0] = f2bf(a0); o[1] = f2bf(a1); o[2] = f2bf(a2); o[3] = f2bf(a3);
        o[4] = f2bf(a4); o[5] = f2bf(a5); o[6] = f2bf(a6); o[7] = f2bf(a7);
        *(short8*)&out[(size_t)bl * D + h * 32 + cg * 8] = o;
    }
}

// ---------------- orchestration ----------------
extern "C" void kernel_launch(void* const* d_in, const int* in_sizes, int n_in,
                              void* d_out, int out_size, void* d_ws, size_t ws_size,
                              hipStream_t stream)
{
    const float* s0    = (const float*)d_in[0];
    const float* p0    = (const float*)d_in[1];
    const float* s1    = (const float*)d_in[2];
    const float* p1    = (const float*)d_in[3];
    const float* s2    = (const float*)d_in[4];
    const float* p2    = (const float*)d_in[5];
    const float* s3    = (const float*)d_in[6];
    const float* p3    = (const float*)d_in[7];
    const float* lvl   = (const float*)d_in[8];
    const float* W_off = (const float*)d_in[9];
    const float* b_off = (const float*)d_in[10];
    const float* W_att = (const float*)d_in[11];
    const float* b_att = (const float*)d_in[12];
    const float* W_val = (const float*)d_in[13];
    const float* b_val = (const float*)d_in[14];
    const float* W_out = (const float*)d_in[15];
    const float* b_out = (const float*)d_in[16];
    const float* ln1g  = (const float*)d_in[17];
    const float* ln1b  = (const float*)d_in[18];
    const float* W1    = (const float*)d_in[19];
    const float* b1    = (const float*)d_in[20];
    const float* W2    = (const float*)d_in[21];
    const float* b2    = (const float*)d_in[22];
    const float* ln2g  = (const float*)d_in[23];
    const float* ln2b  = (const float*)d_in[24];

    const size_t S1 = (size_t)NTOK * D;
    // fp32 region
    float* xbuf = (float*)d_ws;       // S1  : residual stream
    float* pos  = xbuf + S1;          // S1
    float* big  = pos + S1;           // 3*S1: off+attn (ld 768)
    float* bqa  = big + 3 * S1;       // 6*768: packed off/attn bias
    // bf16 region
    short* qbf   = (short*)(bqa + 6 * 768);        // S1 : LN1(x)+pos / LN2(x)
    short* x_bf  = qbf + S1;                       // S1 : bf16 of residual x
    short* valbf = x_bf + S1;                      // S1
    short* sampb = valbf + S1;                     // S1
    short* hidbf = sampb + S1;                     // 4*S1 : FFN hidden
    short* wt_qa  = hidbf + 4 * S1;                // [6][768][256]
    short* wt_val = wt_qa  + (size_t)6 * 768 * 256;
    short* wt_out = wt_val + (size_t)6 * 256 * 256;
    short* wt_1   = wt_out + (size_t)6 * 256 * 256;
    short* wt_2   = wt_1   + (size_t)6 * 1024 * 256;

    // weight prep (bf16 [N][K]); off+attn packed to 768 rows
    wconv_kernel<<<dim3(16, 8, 6), 256, 0, stream>>>(W_off, wt_qa, 256, 512, 768 * 256, 0);
    wconv_kernel<<<dim3(8, 8, 6),  256, 0, stream>>>(W_att, wt_qa, 256, 256, 768 * 256, 512);
    wconv_kernel<<<dim3(8, 8, 6),  256, 0, stream>>>(W_val, wt_val, 256, 256, 256 * 256, 0);
    wconv_kernel<<<dim3(8, 8, 6),  256, 0, stream>>>(W_out, wt_out, 256, 256, 256 * 256, 0);
    wconv_kernel<<<dim3(32, 8, 6), 256, 0, stream>>>(W1,    wt_1,   256, 1024, 1024 * 256, 0);
    wconv_kernel<<<dim3(8, 32, 6), 256, 0, stream>>>(W2,    wt_2,   1024, 256, 256 * 1024, 0);
    bpack_kernel<<<18, 256, 0, stream>>>(b_off, b_att, bqa);

    // flatten
    flat_kernel<<<dim3(128, 8, 2), 256, 0, stream>>>(s0, p0, lvl, xbuf, x_bf, pos, 4096, 0, 0);
    flat_kernel<<<dim3(32, 8, 2),  256, 0, stream>>>(s1, p1, lvl, xbuf, x_bf, pos, 1024, 4096, 1);
    flat_kernel<<<dim3(8, 8, 2),   256, 0, stream>>>(s2, p2, lvl, xbuf, x_bf, pos, 256, 5120, 2);
    flat_kernel<<<dim3(2, 8, 2),   256, 0, stream>>>(s3, p3, lvl, xbuf, x_bf, pos, 64, 5376, 3);

    for (int i = 0; i < 6; ++i) {
        // q = LN1(x) + pos  (bf16)
        ln_kernel<<<NTOK / 4, 256, 0, stream>>>(xbuf, ln1g + i * 256, ln1b + i * 256, pos, qbf);
        // fused: [off|attn] = q @ Wqa -> big (f32, ld 768)  ||  val = x @ W_val -> valbf (bf16)
        mm2_kernel<<<dim3(8, 85), 256, 0, stream>>>(
            qbf, wt_qa + (size_t)i * 768 * 256, bqa + i * 768, big, 768,
            x_bf, wt_val + (size_t)i * 256 * 256, b_val + i * 256, valbf, 256,
            6, 256);
        // deformable sampling
        sample_kernel<<<NTOK, 256, 0, stream>>>(big, valbf, sampb);
        // x = x + samp @ W_out + b_out  (f32)
        mm_kernel<<<dim3(2, 85), 256, 0, stream>>>(
            sampb, wt_out + (size_t)i * 256 * 256, b_out + i * 256, xbuf, xbuf, nullptr, 256, 256, 0);
        // x2 = LN2(x) (bf16)
        ln_kernel<<<NTOK / 4, 256, 0, stream>>>(xbuf, ln2g + i * 256, ln2b + i * 256, nullptr, qbf);
        // h = gelu(x2 @ W1 + b1)  (bf16)
        mm_kernel<<<dim3(8, 85), 256, 0, stream>>>(
            qbf, wt_1 + (size_t)i * 1024 * 256, b1 + i * 1024, nullptr, nullptr, hidbf, 256, 1024, 1);
        // x = x + h @ W2 + b2  (f32; last layer -> d_out; also refresh x_bf for next val GEMM)
        float* outp = (i == 5) ? (float*)d_out : xbuf;
        short* xbp  = (i == 5) ? nullptr : x_bf;
        mm_kernel<<<dim3(2, 85), 256, 0, stream>>>(
            hidbf, wt_2 + (size_t)i * 256 * 1024, b2 + i * 256, xbuf, outp, xbp, 1024, 256, 0);
    }
}

// Round 9
// 793.565 us; speedup vs baseline: 3.8724x; 1.1611x over previous
//
#include <hip/hip_runtime.h>
#include <hip/hip_bf16.h>
#include <math.h>

#define L_TOK 5440
#define NTOK  10880   // B * L
#define D     256

typedef __attribute__((ext_vector_type(8))) short short8;
typedef __attribute__((ext_vector_type(4))) short short4v;
typedef __attribute__((ext_vector_type(4))) float f32x4;

__device__ __forceinline__ short f2bf(float f) {
    __hip_bfloat16 h = __float2bfloat16(f);
    return __builtin_bit_cast(short, h);
}
__device__ __forceinline__ float bf2f(short s) {
    unsigned u = ((unsigned)(unsigned short)s) << 16;
    return __builtin_bit_cast(float, u);
}

#define GLL16(gp, lp) \
    __builtin_amdgcn_global_load_lds((const __attribute__((address_space(1))) void*)(gp), \
                                     (__attribute__((address_space(3))) void*)(lp), 16, 0, 0)

// ---------------- flatten via LDS transpose: (B,d,H,W) -> (B,L,d) f32 + bf16, pos += level_embed
__global__ __launch_bounds__(256) void flat_kernel(
    const float* __restrict__ s, const float* __restrict__ p, const float* __restrict__ le,
    float* __restrict__ x, short* __restrict__ xb, float* __restrict__ pos,
    int HW, int start, int lv)
{
    __shared__ float ts[32][33], tp[32][33];
    int b = blockIdx.z, c0 = blockIdx.y * 32, pix0 = blockIdx.x * 32;
    int tx = threadIdx.x & 31, ty = threadIdx.x >> 5;
#pragma unroll
    for (int i = 0; i < 4; ++i) {
        int c = c0 + ty + i * 8;
        size_t gi = ((size_t)b * D + c) * HW + pix0 + tx;
        ts[ty + i * 8][tx] = s[gi];
        tp[ty + i * 8][tx] = p[gi];
    }
    __syncthreads();
#pragma unroll
    for (int i = 0; i < 4; ++i) {
        int pix = pix0 + ty + i * 8;
        size_t bl = (size_t)b * L_TOK + start + pix;
        int c = c0 + tx;
        float v = ts[tx][ty + i * 8];
        x[bl * D + c]   = v;
        xb[bl * D + c]  = f2bf(v);
        pos[bl * D + c] = tp[tx][ty + i * 8] + le[lv * D + c];
    }
}

// ---------------- weight convert+transpose: W (depth,K,N) f32 -> Wt (depth, rowoff+N, K) bf16 ----
__global__ __launch_bounds__(256) void wconv_kernel(
    const float* __restrict__ W, short* __restrict__ Wt, int K, int N,
    int dstride, int rowoff)
{
    __shared__ float tile[32][33];
    int d = blockIdx.z;
    int n0 = blockIdx.x * 32, k0 = blockIdx.y * 32;
    const float* Wd = W + (size_t)d * K * N;
    short* Wtd = Wt + (size_t)d * dstride + (size_t)rowoff * K;
    int tx = threadIdx.x & 31, ty = threadIdx.x >> 5;
#pragma unroll
    for (int i = 0; i < 4; ++i)
        tile[ty + i * 8][tx] = Wd[(size_t)(k0 + ty + i * 8) * N + n0 + tx];
    __syncthreads();
#pragma unroll
    for (int i = 0; i < 4; ++i)
        Wtd[(size_t)(n0 + ty + i * 8) * K + k0 + tx] = f2bf(tile[tx][ty + i * 8]);
}

// ---------------- pack b_off(512) ++ b_att(256) -> bqa(768) per depth ----------------
__global__ __launch_bounds__(256) void bpack_kernel(
    const float* __restrict__ boff, const float* __restrict__ batt, float* __restrict__ bqa)
{
    int i = blockIdx.x * 256 + threadIdx.x;
    if (i >= 6 * 768) return;
    int d = i / 768, c = i - d * 768;
    bqa[i] = (c < 512) ? boff[d * 512 + c] : batt[d * 256 + c - 512];
}

// ---------------- LayerNorm -> bf16 (one wave per token) ----------------
__global__ __launch_bounds__(256) void ln_kernel(
    const float* __restrict__ x, const float* __restrict__ g, const float* __restrict__ bta,
    const float* __restrict__ pos, short* __restrict__ out)
{
    int wid = threadIdx.x >> 6, lane = threadIdx.x & 63;
    int m = blockIdx.x * 4 + wid;
    const float* xr = x + (size_t)m * D;
    float v[4];
#pragma unroll
    for (int i = 0; i < 4; ++i) v[i] = xr[lane + i * 64];
    float s = v[0] + v[1] + v[2] + v[3];
#pragma unroll
    for (int o = 32; o; o >>= 1) s += __shfl_xor(s, o);
    float mean = s * (1.0f / D);
    float sq = 0.0f;
#pragma unroll
    for (int i = 0; i < 4; ++i) { float d = v[i] - mean; sq += d * d; }
#pragma unroll
    for (int o = 32; o; o >>= 1) sq += __shfl_xor(sq, o);
    float rstd = rsqrtf(sq * (1.0f / D) + 1e-5f);
    short* orow = out + (size_t)m * D;
#pragma unroll
    for (int i = 0; i < 4; ++i) {
        int c = lane + i * 64;
        float o = (v[i] - mean) * rstd * g[c] + bta[c];
        if (pos) o += pos[(size_t)m * D + c];
        orow[c] = f2bf(o);
    }
}

// ---------------- bf16 MFMA GEMM body: out = act(A[M,K] @ Wt[N,K]^T + bias) (+resid) ----------
// BM=64 x BN tile (BN=128 or 64), BK=64, 4 waves; wave w computes all 64 rows x cols
// [w*BN/4, (w+1)*BN/4). Double-buffered LDS + global_load_lds width-16 prefetch:
// STAGE(next) issued BEFORE compute(cur), one barrier per K-step (T3-minimum 2-phase)
// -> HBM/L2 latency hides under MFMA even at low occupancy.
// Swizzle: LDS linear, 16B slot ^= (row&7) applied on the GLOBAL source address
// (rule #21), inverted on the ds_read offsets; fragment reads 2-way max (free).
template<int BN>
__device__ __forceinline__ void mm_body64(
    const short* __restrict__ A, const short* __restrict__ Wt,
    const float* __restrict__ bias, const float* __restrict__ resid,
    float* __restrict__ Cf, short* __restrict__ Cb,
    int row0, int col0, int K, int ldc, int act)
{
    constexpr int NW  = BN / 4;    // per-wave col extent
    constexpr int NF  = NW / 16;   // n-frags per wave
    constexpr int BCH = BN / 32;   // B 8-row chunks per wave
    __shared__ __align__(16) short As[2][64 * 64];
    __shared__ __align__(16) short Bs[2][BN * 64];
    int tid = threadIdx.x, lane = tid & 63, w = tid >> 6;
    int l15 = lane & 15, l16 = lane >> 4;

    int a_off[4][2], b_off[NF][2];
#pragma unroll
    for (int m = 0; m < 4; ++m)
#pragma unroll
        for (int kk = 0; kk < 2; ++kk) {
            int ra = m * 16 + l15;
            a_off[m][kk] = ra * 64 + (((kk * 4 + l16) ^ (ra & 7)) << 3);
        }
#pragma unroll
    for (int n = 0; n < NF; ++n)
#pragma unroll
        for (int kk = 0; kk < 2; ++kk) {
            int rb = w * NW + n * 16 + l15;
            b_off[n][kk] = rb * 64 + (((kk * 4 + l16) ^ (rb & 7)) << 3);
        }

    // staging source addresses (8-row chunks, swizzled 16B slot within the 128B row)
    int sg = (lane & 7) ^ ((lane >> 3) & 7);
    const short* ag = A  + (size_t)(row0 + w * 16 + (lane >> 3)) * K + sg * 8;
    const short* bg = Wt + (size_t)(col0 + w * NW + (lane >> 3)) * K + sg * 8;

    f32x4 acc[4][NF];
#pragma unroll
    for (int m = 0; m < 4; ++m)
#pragma unroll
        for (int n = 0; n < NF; ++n) acc[m][n] = (f32x4){0.f, 0.f, 0.f, 0.f};

    auto stage = [&](int buf, int kofs) {
#pragma unroll
        for (int c = 0; c < 2; ++c)
            GLL16(ag + (size_t)c * 8 * K + kofs, &As[buf][w * 1024 + c * 512]);
#pragma unroll
        for (int c = 0; c < BCH; ++c)
            GLL16(bg + (size_t)c * 8 * K + kofs, &Bs[buf][w * NW * 64 + c * 512]);
    };
    auto comp = [&](int buf) {
#pragma unroll
        for (int kk = 0; kk < 2; ++kk) {
            short8 af[4], bfr[NF];
#pragma unroll
            for (int m = 0; m < 4; ++m) af[m] = *(short8*)&As[buf][a_off[m][kk]];
#pragma unroll
            for (int n = 0; n < NF; ++n) bfr[n] = *(short8*)&Bs[buf][b_off[n][kk]];
#pragma unroll
            for (int m = 0; m < 4; ++m)
#pragma unroll
                for (int n = 0; n < NF; ++n)
                    acc[m][n] = __builtin_amdgcn_mfma_f32_16x16x32_bf16(af[m], bfr[n], acc[m][n], 0, 0, 0);
        }
    };

    stage(0, 0);
    __syncthreads();               // vmcnt(0) drain + sync
    int cur = 0;
    for (int k0 = 64; k0 < K; k0 += 64) {
        stage(cur ^ 1, k0);        // prefetch next K-step
        comp(cur);                 // MFMA on current (hides the loads)
        __syncthreads();           // drains prefetch, protects buf reuse
        cur ^= 1;
    }
    comp(cur);

#pragma unroll
    for (int m = 0; m < 4; ++m) {
#pragma unroll
        for (int j = 0; j < 4; ++j) {
            int row = row0 + m * 16 + l16 * 4 + j;
#pragma unroll
            for (int n = 0; n < NF; ++n) {
                int col = col0 + w * NW + n * 16 + l15;
                float v = acc[m][n][j] + bias[col];
                if (act) v = 0.5f * v * (1.0f + erff(v * 0.70710678118654752f));
                if (resid) v += resid[(size_t)row * ldc + col];
                if (Cf) Cf[(size_t)row * ldc + col] = v;
                if (Cb) Cb[(size_t)row * ldc + col] = f2bf(v);
            }
        }
    }
}

template<int BN>
__global__ __launch_bounds__(256) void mm_kernel(
    const short* __restrict__ A, const short* __restrict__ Wt,
    const float* __restrict__ bias, const float* __restrict__ resid,
    float* __restrict__ Cf, short* __restrict__ Cb, int K, int ldc, int act)
{
    mm_body64<BN>(A, Wt, bias, resid, Cf, Cb, blockIdx.y * 64, blockIdx.x * BN, K, ldc, act);
}

// two independent GEMMs (shared M, K) in one launch: x-blocks [0,nx1) -> #1, rest -> #2
__global__ __launch_bounds__(256) void mm2_kernel(
    const short* __restrict__ A1, const short* __restrict__ Wt1, const float* __restrict__ bias1,
    float* __restrict__ Cf1, int ldc1,
    const short* __restrict__ A2, const short* __restrict__ Wt2, const float* __restrict__ bias2,
    short* __restrict__ Cb2, int ldc2,
    int nx1, int K)
{
    const short *A, *Wt; const float* bias; float* Cf; short* Cb; int ldc, col0;
    if ((int)blockIdx.x < nx1) {
        A = A1; Wt = Wt1; bias = bias1; Cf = Cf1; Cb = nullptr; ldc = ldc1;
        col0 = blockIdx.x * 128;
    } else {
        A = A2; Wt = Wt2; bias = bias2; Cf = nullptr; Cb = Cb2; ldc = ldc2;
        col0 = (blockIdx.x - nx1) * 128;
    }
    mm_body64<128>(A, Wt, bias, nullptr, Cf, Cb, blockIdx.y * 64, col0, K, ldc, 0);
}

// ---------------- deformable sampling (softmax fused, bf16 val, 16B gathers) ----------------
__global__ __launch_bounds__(256) void sample_kernel(
    const float* __restrict__ big, const short* __restrict__ val, short* __restrict__ out)
{
    __shared__ float sw[8 * 132];
    __shared__ int   si[8 * 132];
    int bl = blockIdx.x;
    int b = bl / L_TOK, l = bl - b * L_TOK;
    const float* row = big + (size_t)bl * 768;
    int t = threadIdx.x;
    {
        int head = t >> 5, lvp = t & 31, lv = lvp >> 3, p = lvp & 7;
        int lq, r;
        if (l < 4096)      { lq = 0; r = l;        }
        else if (l < 5120) { lq = 1; r = l - 4096; }
        else if (l < 5376) { lq = 2; r = l - 5120; }
        else               { lq = 3; r = l - 5376; }
        int sh = 6 - lq;
        float invSq = 1.0f / (float)(1 << sh);
        float refx = ((r & ((1 << sh) - 1)) + 0.5f) * invSq;
        float refy = ((r >> sh) + 0.5f) * invSq;
        int S = 64 >> lv;
        int start = (lv == 0) ? 0 : (lv == 1) ? 4096 : (lv == 2) ? 5120 : 5376;
        float Sf = (float)S;
        float logit = row[512 + head * 32 + lvp];
        float mx = logit;
#pragma unroll
        for (int o = 16; o; o >>= 1) mx = fmaxf(mx, __shfl_xor(mx, o));
        float e = __expf(logit - mx);
        float ssum = e;
#pragma unroll
        for (int o = 16; o; o >>= 1) ssum += __shfl_xor(ssum, o);
        float a = e / ssum;
        float ox = row[head * 64 + lv * 16 + p * 2 + 0];
        float oy = row[head * 64 + lv * 16 + p * 2 + 1];
        float X = refx * Sf + ox - 0.5f;
        float Y = refy * Sf + oy - 0.5f;
        float x0 = floorf(X), y0 = floorf(Y);
        float fx = X - x0, fy = Y - y0;
        int xi0 = (int)x0, yi0 = (int)y0;
        int qt = lvp >> 3, sidx = lvp & 7;
        int base_w = head * 132 + qt * 33 + sidx * 4;
#pragma unroll
        for (int tap = 0; tap < 4; ++tap) {
            int dx = tap & 1, dy = tap >> 1;
            int xi = xi0 + dx, yi = yi0 + dy;
            float wgt = (dx ? fx : 1.0f - fx) * (dy ? fy : 1.0f - fy);
            bool valid = (xi >= 0) && (xi < S) && (yi >= 0) && (yi < S);
            int xc = xi < 0 ? 0 : (xi > S - 1 ? S - 1 : xi);
            int yc = yi < 0 ? 0 : (yi > S - 1 ? S - 1 : yi);
            sw[base_w + tap] = valid ? wgt * a : 0.0f;
            si[base_w + tap] = start + yc * S + xc;
        }
    }
    __syncthreads();
    int h = t >> 5, sgp = (t >> 2) & 7, cg = t & 3;
    const short* vb = val + (size_t)b * L_TOK * D + h * 32 + cg * 8;
    float a0 = 0.f, a1 = 0.f, a2 = 0.f, a3 = 0.f;
    float a4 = 0.f, a5 = 0.f, a6 = 0.f, a7 = 0.f;
#pragma unroll
    for (int ss = 0; ss < 4; ++ss) {
        int base = h * 132 + ss * 33 + sgp * 4;
#pragma unroll
        for (int tap = 0; tap < 4; ++tap) {
            float wgt = sw[base + tap];
            int   idx = si[base + tap];
            const short8 g = *(const short8*)&vb[(size_t)idx * D];
            a0 += wgt * bf2f(g[0]); a1 += wgt * bf2f(g[1]);
            a2 += wgt * bf2f(g[2]); a3 += wgt * bf2f(g[3]);
            a4 += wgt * bf2f(g[4]); a5 += wgt * bf2f(g[5]);
            a6 += wgt * bf2f(g[6]); a7 += wgt * bf2f(g[7]);
        }
    }
#pragma unroll
    for (int o = 4; o <= 16; o <<= 1) {
        a0 += __shfl_xor(a0, o); a1 += __shfl_xor(a1, o);
        a2 += __shfl_xor(a2, o); a3 += __shfl_xor(a3, o);
        a4 += __shfl_xor(a4, o); a5 += __shfl_xor(a5, o);
        a6 += __shfl_xor(a6, o); a7 += __shfl_xor(a7, o);
    }
    if (sgp == 0) {
        short8 o;
        o[0] = f2bf(a0); o[1] = f2bf(a1); o[2] = f2bf(a2); o[3] = f2bf(a3);
        o[4] = f2bf(a4); o[5] = f2bf(a5); o[6] = f2bf(a6); o[7] = f2bf(a7);
        *(short8*)&out[(size_t)bl * D + h * 32 + cg * 8] = o;
    }
}

// ---------------- orchestration ----------------
extern "C" void kernel_launch(void* const* d_in, const int* in_sizes, int n_in,
                              void* d_out, int out_size, void* d_ws, size_t ws_size,
                              hipStream_t stream)
{
    const float* s0    = (const float*)d_in[0];
    const float* p0    = (const float*)d_in[1];
    const float* s1    = (const float*)d_in[2];
    const float* p1    = (const float*)d_in[3];
    const float* s2    = (const float*)d_in[4];
    const float* p2    = (const float*)d_in[5];
    const float* s3    = (const float*)d_in[6];
    const float* p3    = (const float*)d_in[7];
    const float* lvl   = (const float*)d_in[8];
    const float* W_off = (const float*)d_in[9];
    const float* b_off = (const float*)d_in[10];
    const float* W_att = (const float*)d_in[11];
    const float* b_att = (const float*)d_in[12];
    const float* W_val = (const float*)d_in[13];
    const float* b_val = (const float*)d_in[14];
    const float* W_out = (const float*)d_in[15];
    const float* b_out = (const float*)d_in[16];
    const float* ln1g  = (const float*)d_in[17];
    const float* ln1b  = (const float*)d_in[18];
    const float* W1    = (const float*)d_in[19];
    const float* b1    = (const float*)d_in[20];
    const float* W2    = (const float*)d_in[21];
    const float* b2    = (const float*)d_in[22];
    const float* ln2g  = (const float*)d_in[23];
    const float* ln2b  = (const float*)d_in[24];

    const size_t S1 = (size_t)NTOK * D;
    // fp32 region
    float* xbuf = (float*)d_ws;       // S1  : residual stream
    float* pos  = xbuf + S1;          // S1
    float* big  = pos + S1;           // 3*S1: off+attn (ld 768)
    float* bqa  = big + 3 * S1;       // 6*768: packed off/attn bias
    // bf16 region
    short* qbf   = (short*)(bqa + 6 * 768);        // S1 : LN1(x)+pos / LN2(x)
    short* x_bf  = qbf + S1;                       // S1 : bf16 of residual x
    short* valbf = x_bf + S1;                      // S1
    short* sampb = valbf + S1;                     // S1
    short* hidbf = sampb + S1;                     // 4*S1 : FFN hidden
    short* wt_qa  = hidbf + 4 * S1;                // [6][768][256]
    short* wt_val = wt_qa  + (size_t)6 * 768 * 256;
    short* wt_out = wt_val + (size_t)6 * 256 * 256;
    short* wt_1   = wt_out + (size_t)6 * 256 * 256;
    short* wt_2   = wt_1   + (size_t)6 * 1024 * 256;

    // weight prep (bf16 [N][K]); off+attn packed to 768 rows
    wconv_kernel<<<dim3(16, 8, 6), 256, 0, stream>>>(W_off, wt_qa, 256, 512, 768 * 256, 0);
    wconv_kernel<<<dim3(8, 8, 6),  256, 0, stream>>>(W_att, wt_qa, 256, 256, 768 * 256, 512);
    wconv_kernel<<<dim3(8, 8, 6),  256, 0, stream>>>(W_val, wt_val, 256, 256, 256 * 256, 0);
    wconv_kernel<<<dim3(8, 8, 6),  256, 0, stream>>>(W_out, wt_out, 256, 256, 256 * 256, 0);
    wconv_kernel<<<dim3(32, 8, 6), 256, 0, stream>>>(W1,    wt_1,   256, 1024, 1024 * 256, 0);
    wconv_kernel<<<dim3(8, 32, 6), 256, 0, stream>>>(W2,    wt_2,   1024, 256, 256 * 1024, 0);
    bpack_kernel<<<18, 256, 0, stream>>>(b_off, b_att, bqa);

    // flatten
    flat_kernel<<<dim3(128, 8, 2), 256, 0, stream>>>(s0, p0, lvl, xbuf, x_bf, pos, 4096, 0, 0);
    flat_kernel<<<dim3(32, 8, 2),  256, 0, stream>>>(s1, p1, lvl, xbuf, x_bf, pos, 1024, 4096, 1);
    flat_kernel<<<dim3(8, 8, 2),   256, 0, stream>>>(s2, p2, lvl, xbuf, x_bf, pos, 256, 5120, 2);
    flat_kernel<<<dim3(2, 8, 2),   256, 0, stream>>>(s3, p3, lvl, xbuf, x_bf, pos, 64, 5376, 3);

    for (int i = 0; i < 6; ++i) {
        // q = LN1(x) + pos  (bf16)
        ln_kernel<<<NTOK / 4, 256, 0, stream>>>(xbuf, ln1g + i * 256, ln1b + i * 256, pos, qbf);
        // fused: [off|attn] = q @ Wqa -> big (f32, ld 768)  ||  val = x @ W_val -> valbf (bf16)
        mm2_kernel<<<dim3(8, 170), 256, 0, stream>>>(
            qbf, wt_qa + (size_t)i * 768 * 256, bqa + i * 768, big, 768,
            x_bf, wt_val + (size_t)i * 256 * 256, b_val + i * 256, valbf, 256,
            6, 256);
        // deformable sampling
        sample_kernel<<<NTOK, 256, 0, stream>>>(big, valbf, sampb);
        // x = x + samp @ W_out + b_out  (f32)
        mm_kernel<64><<<dim3(4, 170), 256, 0, stream>>>(
            sampb, wt_out + (size_t)i * 256 * 256, b_out + i * 256, xbuf, xbuf, nullptr, 256, 256, 0);
        // x2 = LN2(x) (bf16)
        ln_kernel<<<NTOK / 4, 256, 0, stream>>>(xbuf, ln2g + i * 256, ln2b + i * 256, nullptr, qbf);
        // h = gelu(x2 @ W1 + b1)  (bf16)
        mm_kernel<128><<<dim3(8, 170), 256, 0, stream>>>(
            qbf, wt_1 + (size_t)i * 1024 * 256, b1 + i * 1024, nullptr, nullptr, hidbf, 256, 1024, 1);
        // x = x + h @ W2 + b2  (f32; last layer -> d_out; also refresh x_bf for next val GEMM)
        float* outp = (i == 5) ? (float*)d_out : xbuf;
        short* xbp  = (i == 5) ? nullptr : x_bf;
        mm_kernel<64><<<dim3(4, 170), 256, 0, stream>>>(
            hidbf, wt_2 + (size_t)i * 256 * 1024, b2 + i * 256, xbuf, outp, xbp, 1024, 256, 0);
    }
}

// Round 10
// 778.288 us; speedup vs baseline: 3.9485x; 1.0196x over previous
//
#include <hip/hip_runtime.h>
#include <hip/hip_bf16.h>
#include <math.h>

#define L_TOK 5440
#define NTOK  10880   // B * L
#define D     256

typedef __attribute__((ext_vector_type(8))) short short8;
typedef __attribute__((ext_vector_type(4))) float f32x4;

__device__ __forceinline__ short f2bf(float f) {
    __hip_bfloat16 h = __float2bfloat16(f);
    return __builtin_bit_cast(short, h);
}
__device__ __forceinline__ float bf2f(short s) {
    unsigned u = ((unsigned)(unsigned short)s) << 16;
    return __builtin_bit_cast(float, u);
}

#define GLL16(gp, lp) \
    __builtin_amdgcn_global_load_lds((const __attribute__((address_space(1))) void*)(gp), \
                                     (__attribute__((address_space(3))) void*)(lp), 16, 0, 0)

// ---------------- flatten via LDS transpose: (B,d,H,W) -> (B,L,d) f32 + bf16, pos += level_embed
__global__ __launch_bounds__(256) void flat_kernel(
    const float* __restrict__ s, const float* __restrict__ p, const float* __restrict__ le,
    float* __restrict__ x, short* __restrict__ xb, float* __restrict__ pos,
    int HW, int start, int lv)
{
    __shared__ float ts[32][33], tp[32][33];
    int b = blockIdx.z, c0 = blockIdx.y * 32, pix0 = blockIdx.x * 32;
    int tx = threadIdx.x & 31, ty = threadIdx.x >> 5;
#pragma unroll
    for (int i = 0; i < 4; ++i) {
        int c = c0 + ty + i * 8;
        size_t gi = ((size_t)b * D + c) * HW + pix0 + tx;
        ts[ty + i * 8][tx] = s[gi];
        tp[ty + i * 8][tx] = p[gi];
    }
    __syncthreads();
#pragma unroll
    for (int i = 0; i < 4; ++i) {
        int pix = pix0 + ty + i * 8;
        size_t bl = (size_t)b * L_TOK + start + pix;
        int c = c0 + tx;
        float v = ts[tx][ty + i * 8];
        x[bl * D + c]   = v;
        xb[bl * D + c]  = f2bf(v);
        pos[bl * D + c] = tp[tx][ty + i * 8] + le[lv * D + c];
    }
}

// ---------------- weight convert+transpose: W (depth,K,N) f32 -> Wt (depth, rowoff+N, K) bf16 ----
__global__ __launch_bounds__(256) void wconv_kernel(
    const float* __restrict__ W, short* __restrict__ Wt, int K, int N,
    int dstride, int rowoff)
{
    __shared__ float tile[32][33];
    int d = blockIdx.z;
    int n0 = blockIdx.x * 32, k0 = blockIdx.y * 32;
    const float* Wd = W + (size_t)d * K * N;
    short* Wtd = Wt + (size_t)d * dstride + (size_t)rowoff * K;
    int tx = threadIdx.x & 31, ty = threadIdx.x >> 5;
#pragma unroll
    for (int i = 0; i < 4; ++i)
        tile[ty + i * 8][tx] = Wd[(size_t)(k0 + ty + i * 8) * N + n0 + tx];
    __syncthreads();
#pragma unroll
    for (int i = 0; i < 4; ++i)
        Wtd[(size_t)(n0 + ty + i * 8) * K + k0 + tx] = f2bf(tile[tx][ty + i * 8]);
}

// ---------------- pack b_off(512) ++ b_att(256) -> bqa(768) per depth ----------------
__global__ __launch_bounds__(256) void bpack_kernel(
    const float* __restrict__ boff, const float* __restrict__ batt, float* __restrict__ bqa)
{
    int i = blockIdx.x * 256 + threadIdx.x;
    if (i >= 6 * 768) return;
    int d = i / 768, c = i - d * 768;
    bqa[i] = (c < 512) ? boff[d * 512 + c] : batt[d * 256 + c - 512];
}

// ---------------- LayerNorm -> bf16 (one wave per token) ----------------
__global__ __launch_bounds__(256) void ln_kernel(
    const float* __restrict__ x, const float* __restrict__ g, const float* __restrict__ bta,
    const float* __restrict__ pos, short* __restrict__ out)
{
    int wid = threadIdx.x >> 6, lane = threadIdx.x & 63;
    int m = blockIdx.x * 4 + wid;
    const float* xr = x + (size_t)m * D;
    float v[4];
#pragma unroll
    for (int i = 0; i < 4; ++i) v[i] = xr[lane + i * 64];
    float s = v[0] + v[1] + v[2] + v[3];
#pragma unroll
    for (int o = 32; o; o >>= 1) s += __shfl_xor(s, o);
    float mean = s * (1.0f / D);
    float sq = 0.0f;
#pragma unroll
    for (int i = 0; i < 4; ++i) { float d = v[i] - mean; sq += d * d; }
#pragma unroll
    for (int o = 32; o; o >>= 1) sq += __shfl_xor(sq, o);
    float rstd = rsqrtf(sq * (1.0f / D) + 1e-5f);
    short* orow = out + (size_t)m * D;
#pragma unroll
    for (int i = 0; i < 4; ++i) {
        int c = lane + i * 64;
        float o = (v[i] - mean) * rstd * g[c] + bta[c];
        if (pos) o += pos[(size_t)m * D + c];
        orow[c] = f2bf(o);
    }
}

// ---------------- bf16 MFMA GEMM body (BM=64 x BN, BK=64, 4 waves, 2-phase dbuf) --------------
// Staging: global_load_lds width-16, LDS linear; 16B-slot swizzle (slot ^= row&7) applied on the
// GLOBAL source address, inverted on ds_read offsets (rule #21). Fragment reads 2-way max (free).
// Cb output format: f16out ? f16 : bf16.
template<int BN>
__device__ __forceinline__ void mm_body64(
    const short* __restrict__ A, const short* __restrict__ Wt,
    const float* __restrict__ bias, const float* __restrict__ resid,
    float* __restrict__ Cf, short* __restrict__ Cb,
    int row0, int col0, int K, int ldc, int act, int f16out)
{
    constexpr int NW  = BN / 4;    // per-wave col extent
    constexpr int NF  = NW / 16;   // n-frags per wave
    constexpr int BCH = BN / 32;   // B 8-row chunks per wave
    __shared__ __align__(16) short As[2][64 * 64];
    __shared__ __align__(16) short Bs[2][BN * 64];
    int tid = threadIdx.x, lane = tid & 63, w = tid >> 6;
    int l15 = lane & 15, l16 = lane >> 4;

    int a_off[4][2], b_off[NF][2];
#pragma unroll
    for (int m = 0; m < 4; ++m)
#pragma unroll
        for (int kk = 0; kk < 2; ++kk) {
            int ra = m * 16 + l15;
            a_off[m][kk] = ra * 64 + (((kk * 4 + l16) ^ (ra & 7)) << 3);
        }
#pragma unroll
    for (int n = 0; n < NF; ++n)
#pragma unroll
        for (int kk = 0; kk < 2; ++kk) {
            int rb = w * NW + n * 16 + l15;
            b_off[n][kk] = rb * 64 + (((kk * 4 + l16) ^ (rb & 7)) << 3);
        }

    int sg = (lane & 7) ^ ((lane >> 3) & 7);
    const short* ag = A  + (size_t)(row0 + w * 16 + (lane >> 3)) * K + sg * 8;
    const short* bg = Wt + (size_t)(col0 + w * NW + (lane >> 3)) * K + sg * 8;

    f32x4 acc[4][NF];
#pragma unroll
    for (int m = 0; m < 4; ++m)
#pragma unroll
        for (int n = 0; n < NF; ++n) acc[m][n] = (f32x4){0.f, 0.f, 0.f, 0.f};

    auto stage = [&](int buf, int kofs) {
#pragma unroll
        for (int c = 0; c < 2; ++c)
            GLL16(ag + (size_t)c * 8 * K + kofs, &As[buf][w * 1024 + c * 512]);
#pragma unroll
        for (int c = 0; c < BCH; ++c)
            GLL16(bg + (size_t)c * 8 * K + kofs, &Bs[buf][w * NW * 64 + c * 512]);
    };
    auto comp = [&](int buf) {
#pragma unroll
        for (int kk = 0; kk < 2; ++kk) {
            short8 af[4], bfr[NF];
#pragma unroll
            for (int m = 0; m < 4; ++m) af[m] = *(short8*)&As[buf][a_off[m][kk]];
#pragma unroll
            for (int n = 0; n < NF; ++n) bfr[n] = *(short8*)&Bs[buf][b_off[n][kk]];
#pragma unroll
            for (int m = 0; m < 4; ++m)
#pragma unroll
                for (int n = 0; n < NF; ++n)
                    acc[m][n] = __builtin_amdgcn_mfma_f32_16x16x32_bf16(af[m], bfr[n], acc[m][n], 0, 0, 0);
        }
    };

    stage(0, 0);
    __syncthreads();
    int cur = 0;
    for (int k0 = 64; k0 < K; k0 += 64) {
        stage(cur ^ 1, k0);
        comp(cur);
        __syncthreads();
        cur ^= 1;
    }
    comp(cur);

#pragma unroll
    for (int m = 0; m < 4; ++m) {
#pragma unroll
        for (int j = 0; j < 4; ++j) {
            int row = row0 + m * 16 + l16 * 4 + j;
#pragma unroll
            for (int n = 0; n < NF; ++n) {
                int col = col0 + w * NW + n * 16 + l15;
                float v = acc[m][n][j] + bias[col];
                if (act) v = 0.5f * v * (1.0f + erff(v * 0.70710678118654752f));
                if (resid) v += resid[(size_t)row * ldc + col];
                if (Cf) Cf[(size_t)row * ldc + col] = v;
                if (Cb) Cb[(size_t)row * ldc + col] =
                    f16out ? __builtin_bit_cast(short, (_Float16)v) : f2bf(v);
            }
        }
    }
}

template<int BN>
__global__ __launch_bounds__(256) void mm_kernel(
    const short* __restrict__ A, const short* __restrict__ Wt,
    const float* __restrict__ bias, const float* __restrict__ resid,
    float* __restrict__ Cf, short* __restrict__ Cb, int K, int ldc, int act)
{
    mm_body64<BN>(A, Wt, bias, resid, Cf, Cb, blockIdx.y * 64, blockIdx.x * BN, K, ldc, act, 0);
}

// two independent GEMMs (shared M, K): #1 -> f16 out (big), #2 -> bf16 out (val)
__global__ __launch_bounds__(256) void mm2_kernel(
    const short* __restrict__ A1, const short* __restrict__ Wt1, const float* __restrict__ bias1,
    short* __restrict__ C1, int ldc1,
    const short* __restrict__ A2, const short* __restrict__ Wt2, const float* __restrict__ bias2,
    short* __restrict__ C2, int ldc2,
    int nx1, int K)
{
    const short *A, *Wt; const float* bias; short* Cb; int ldc, col0, f16o;
    if ((int)blockIdx.x < nx1) {
        A = A1; Wt = Wt1; bias = bias1; Cb = C1; ldc = ldc1; f16o = 1;
        col0 = blockIdx.x * 128;
    } else {
        A = A2; Wt = Wt2; bias = bias2; Cb = C2; ldc = ldc2; f16o = 0;
        col0 = (blockIdx.x - nx1) * 128;
    }
    mm_body64<128>(A, Wt, bias, nullptr, nullptr, Cb, blockIdx.y * 64, col0, K, ldc, 0, f16o);
}

// ---------------- deformable sampling (softmax fused, f16 big, bf16 val, batched gathers) -----
// big row (f16): [0:512) = off (h,lv,p,2), [512:768) = attn logits (h, lv*8+p)
// phase1 stores weight + PRE-SCALED element offset (idx*D) into padded LDS (reads <=2-way).
// phase2: t = h*32 + sgp*4 + cg ; 2 groups of 8 gathers: load 8 (w,idx) pairs, issue 8
// short8 loads (explicit ILP; all compile-time indices), then FMA; shfl-reduce over sgp.
__global__ __launch_bounds__(256) void sample_kernel(
    const short* __restrict__ big, const short* __restrict__ val, short* __restrict__ out)
{
    __shared__ float sw[8 * 132];
    __shared__ int   si[8 * 132];
    int bl = blockIdx.x;
    int b = bl / L_TOK, l = bl - b * L_TOK;
    const _Float16* row = (const _Float16*)big + (size_t)bl * 768;
    int t = threadIdx.x;
    {
        int head = t >> 5, lvp = t & 31, lv = lvp >> 3, p = lvp & 7;
        int lq, r;
        if (l < 4096)      { lq = 0; r = l;        }
        else if (l < 5120) { lq = 1; r = l - 4096; }
        else if (l < 5376) { lq = 2; r = l - 5120; }
        else               { lq = 3; r = l - 5376; }
        int sh = 6 - lq;
        float invSq = 1.0f / (float)(1 << sh);
        float refx = ((r & ((1 << sh) - 1)) + 0.5f) * invSq;
        float refy = ((r >> sh) + 0.5f) * invSq;
        int S = 64 >> lv;
        int start = (lv == 0) ? 0 : (lv == 1) ? 4096 : (lv == 2) ? 5120 : 5376;
        float Sf = (float)S;
        float logit = (float)row[512 + head * 32 + lvp];
        float mx = logit;
#pragma unroll
        for (int o = 16; o; o >>= 1) mx = fmaxf(mx, __shfl_xor(mx, o));
        float e = __expf(logit - mx);
        float ssum = e;
#pragma unroll
        for (int o = 16; o; o >>= 1) ssum += __shfl_xor(ssum, o);
        float a = e / ssum;
        float ox = (float)row[head * 64 + lv * 16 + p * 2 + 0];
        float oy = (float)row[head * 64 + lv * 16 + p * 2 + 1];
        float X = refx * Sf + ox - 0.5f;
        float Y = refy * Sf + oy - 0.5f;
        float x0 = floorf(X), y0 = floorf(Y);
        float fx = X - x0, fy = Y - y0;
        int xi0 = (int)x0, yi0 = (int)y0;
        int qt = lvp >> 3, sidx = lvp & 7;
        int base_w = head * 132 + qt * 33 + sidx * 4;
#pragma unroll
        for (int tap = 0; tap < 4; ++tap) {
            int dx = tap & 1, dy = tap >> 1;
            int xi = xi0 + dx, yi = yi0 + dy;
            float wgt = (dx ? fx : 1.0f - fx) * (dy ? fy : 1.0f - fy);
            bool valid = (xi >= 0) && (xi < S) && (yi >= 0) && (yi < S);
            int xc = xi < 0 ? 0 : (xi > S - 1 ? S - 1 : xi);
            int yc = yi < 0 ? 0 : (yi > S - 1 ? S - 1 : yi);
            sw[base_w + tap] = valid ? wgt * a : 0.0f;
            si[base_w + tap] = (start + yc * S + xc) << 8;   // pre-scaled by D=256
        }
    }
    __syncthreads();
    int h = t >> 5, sgp = (t >> 2) & 7, cg = t & 3;
    const short* vb = val + (size_t)b * L_TOK * D + h * 32 + cg * 8;
    float a0 = 0.f, a1 = 0.f, a2 = 0.f, a3 = 0.f;
    float a4 = 0.f, a5 = 0.f, a6 = 0.f, a7 = 0.f;
#pragma unroll
    for (int gp = 0; gp < 2; ++gp) {
        float w8[8]; int i8[8];
#pragma unroll
        for (int ss = 0; ss < 2; ++ss) {
            int base = h * 132 + (gp * 2 + ss) * 33 + sgp * 4;
#pragma unroll
            for (int tap = 0; tap < 4; ++tap) {
                w8[ss * 4 + tap] = sw[base + tap];
                i8[ss * 4 + tap] = si[base + tap];
            }
        }
        short8 g[8];
#pragma unroll
        for (int k = 0; k < 8; ++k) g[k] = *(const short8*)&vb[i8[k]];
#pragma unroll
        for (int k = 0; k < 8; ++k) {
            float wgt = w8[k];
            a0 += wgt * bf2f(g[k][0]); a1 += wgt * bf2f(g[k][1]);
            a2 += wgt * bf2f(g[k][2]); a3 += wgt * bf2f(g[k][3]);
            a4 += wgt * bf2f(g[k][4]); a5 += wgt * bf2f(g[k][5]);
            a6 += wgt * bf2f(g[k][6]); a7 += wgt * bf2f(g[k][7]);
        }
    }
#pragma unroll
    for (int o = 4; o <= 16; o <<= 1) {
        a0 += __shfl_xor(a0, o); a1 += __shfl_xor(a1, o);
        a2 += __shfl_xor(a2, o); a3 += __shfl_xor(a3, o);
        a4 += __shfl_xor(a4, o); a5 += __shfl_xor(a5, o);
        a6 += __shfl_xor(a6, o); a7 += __shfl_xor(a7, o);
    }
    if (sgp == 0) {
        short8 o;
        o[0] = f2bf(a0); o[1] = f2bf(a1); o[2] = f2bf(a2); o[3] = f2bf(a3);
        o[4] = f2bf(a4); o[5] = f2bf(a5); o[6] = f2bf(a6); o[7] = f2bf(a7);
        *(short8*)&out[(size_t)bl * D + h * 32 + cg * 8] = o;
    }
}

// ---------------- orchestration ----------------
extern "C" void kernel_launch(void* const* d_in, const int* in_sizes, int n_in,
                              void* d_out, int out_size, void* d_ws, size_t ws_size,
                              hipStream_t stream)
{
    const float* s0    = (const float*)d_in[0];
    const float* p0    = (const float*)d_in[1];
    const float* s1    = (const float*)d_in[2];
    const float* p1    = (const float*)d_in[3];
    const float* s2    = (const float*)d_in[4];
    const float* p2    = (const float*)d_in[5];
    const float* s3    = (const float*)d_in[6];
    const float* p3    = (const float*)d_in[7];
    const float* lvl   = (const float*)d_in[8];
    const float* W_off = (const float*)d_in[9];
    const float* b_off = (const float*)d_in[10];
    const float* W_att = (const float*)d_in[11];
    const float* b_att = (const float*)d_in[12];
    const float* W_val = (const float*)d_in[13];
    const float* b_val = (const float*)d_in[14];
    const float* W_out = (const float*)d_in[15];
    const float* b_out = (const float*)d_in[16];
    const float* ln1g  = (const float*)d_in[17];
    const float* ln1b  = (const float*)d_in[18];
    const float* W1    = (const float*)d_in[19];
    const float* b1    = (const float*)d_in[20];
    const float* W2    = (const float*)d_in[21];
    const float* b2    = (const float*)d_in[22];
    const float* ln2g  = (const float*)d_in[23];
    const float* ln2b  = (const float*)d_in[24];

    const size_t S1 = (size_t)NTOK * D;
    // fp32 region
    float* xbuf = (float*)d_ws;       // S1  : residual stream
    float* pos  = xbuf + S1;          // S1
    float* bigf = pos + S1;           // 3*S1 reserved; used as f16 (768 per token)
    float* bqa  = bigf + 3 * S1;      // 6*768: packed off/attn bias
    short* big  = (short*)bigf;
    // bf16 region
    short* qbf   = (short*)(bqa + 6 * 768);        // S1 : LN1(x)+pos / LN2(x)
    short* x_bf  = qbf + S1;                       // S1 : bf16 of residual x
    short* valbf = x_bf + S1;                      // S1
    short* sampb = valbf + S1;                     // S1
    short* hidbf = sampb + S1;                     // 4*S1 : FFN hidden
    short* wt_qa  = hidbf + 4 * S1;                // [6][768][256]
    short* wt_val = wt_qa  + (size_t)6 * 768 * 256;
    short* wt_out = wt_val + (size_t)6 * 256 * 256;
    short* wt_1   = wt_out + (size_t)6 * 256 * 256;
    short* wt_2   = wt_1   + (size_t)6 * 1024 * 256;

    // weight prep (bf16 [N][K]); off+attn packed to 768 rows
    wconv_kernel<<<dim3(16, 8, 6), 256, 0, stream>>>(W_off, wt_qa, 256, 512, 768 * 256, 0);
    wconv_kernel<<<dim3(8, 8, 6),  256, 0, stream>>>(W_att, wt_qa, 256, 256, 768 * 256, 512);
    wconv_kernel<<<dim3(8, 8, 6),  256, 0, stream>>>(W_val, wt_val, 256, 256, 256 * 256, 0);
    wconv_kernel<<<dim3(8, 8, 6),  256, 0, stream>>>(W_out, wt_out, 256, 256, 256 * 256, 0);
    wconv_kernel<<<dim3(32, 8, 6), 256, 0, stream>>>(W1,    wt_1,   256, 1024, 1024 * 256, 0);
    wconv_kernel<<<dim3(8, 32, 6), 256, 0, stream>>>(W2,    wt_2,   1024, 256, 256 * 1024, 0);
    bpack_kernel<<<18, 256, 0, stream>>>(b_off, b_att, bqa);

    // flatten
    flat_kernel<<<dim3(128, 8, 2), 256, 0, stream>>>(s0, p0, lvl, xbuf, x_bf, pos, 4096, 0, 0);
    flat_kernel<<<dim3(32, 8, 2),  256, 0, stream>>>(s1, p1, lvl, xbuf, x_bf, pos, 1024, 4096, 1);
    flat_kernel<<<dim3(8, 8, 2),   256, 0, stream>>>(s2, p2, lvl, xbuf, x_bf, pos, 256, 5120, 2);
    flat_kernel<<<dim3(2, 8, 2),   256, 0, stream>>>(s3, p3, lvl, xbuf, x_bf, pos, 64, 5376, 3);

    for (int i = 0; i < 6; ++i) {
        // q = LN1(x) + pos  (bf16)
        ln_kernel<<<NTOK / 4, 256, 0, stream>>>(xbuf, ln1g + i * 256, ln1b + i * 256, pos, qbf);
        // fused: [off|attn] = q @ Wqa -> big (f16, ld 768)  ||  val = x @ W_val -> valbf (bf16)
        mm2_kernel<<<dim3(8, 170), 256, 0, stream>>>(
            qbf, wt_qa + (size_t)i * 768 * 256, bqa + i * 768, big, 768,
            x_bf, wt_val + (size_t)i * 256 * 256, b_val + i * 256, valbf, 256,
            6, 256);
        // deformable sampling
        sample_kernel<<<NTOK, 256, 0, stream>>>(big, valbf, sampb);
        // x = x + samp @ W_out + b_out  (f32)
        mm_kernel<64><<<dim3(4, 170), 256, 0, stream>>>(
            sampb, wt_out + (size_t)i * 256 * 256, b_out + i * 256, xbuf, xbuf, nullptr, 256, 256, 0);
        // x2 = LN2(x) (bf16)
        ln_kernel<<<NTOK / 4, 256, 0, stream>>>(xbuf, ln2g + i * 256, ln2b + i * 256, nullptr, qbf);
        // h = gelu(x2 @ W1 + b1)  (bf16)
        mm_kernel<128><<<dim3(8, 170), 256, 0, stream>>>(
            qbf, wt_1 + (size_t)i * 1024 * 256, b1 + i * 1024, nullptr, nullptr, hidbf, 256, 1024, 1);
        // x = x + h @ W2 + b2  (f32; last layer -> d_out; also refresh x_bf for next val GEMM)
        float* outp = (i == 5) ? (float*)d_out : xbuf;
        short* xbp  = (i == 5) ? nullptr : x_bf;
        mm_kernel<64><<<dim3(4, 170), 256, 0, stream>>>(
            hidbf, wt_2 + (size_t)i * 256 * 1024, b2 + i * 256, xbuf, outp, xbp, 1024, 256, 0);
    }
}